// Round 1
// baseline (2307.523 us; speedup 1.0000x reference)
//
#include <hip/hip_runtime.h>

#define DF 96
#define GROWS 64
#define PADX 100
#define BN_EPS 1e-5f
#define SLOPE 0.05f

// ---------------- small prep kernels ----------------

__global__ __launch_bounds__(256) void k_init_deg(float* __restrict__ deg, int n) {
    int i = blockIdx.x * 256 + threadIdx.x;
    if (i < n) deg[i] = 1.0f;  // self-loop
}

__global__ __launch_bounds__(128) void k_bn(const float* __restrict__ gamma,
                                            const float* __restrict__ beta,
                                            const float* __restrict__ mean,
                                            const float* __restrict__ var,
                                            float* __restrict__ bnscale,
                                            float* __restrict__ bnbias) {
    int c = threadIdx.x;
    if (c < DF) {
        float s = gamma[c] * rsqrtf(var[c] + BN_EPS);
        bnscale[c] = s;
        bnbias[c]  = beta[c] - mean[c] * s;
    }
}

__global__ __launch_bounds__(256) void k_deg(const int* __restrict__ ei,
                                             float* __restrict__ deg, int E) {
    int e = blockIdx.x * 256 + threadIdx.x;
    if (e < E) atomicAdd(&deg[ei[E + e]], 1.0f);  // dst row of edge_index
}

__global__ __launch_bounds__(256) void k_dinv(const float* __restrict__ deg,
                                              float* __restrict__ dinv, int n) {
    int i = blockIdx.x * 256 + threadIdx.x;
    if (i < n) dinv[i] = rsqrtf(deg[i]);  // deg >= 1 always
}

// ---------------- GEMM: hs = transform(in) @ W * dinv[row] ----------------
// LAYER==0: transform = identity (in = node_feat)
// LAYER==1: transform = BN(LeakyReLU(dinv[row]*in + b1))   (in = acc1)
// Writes hs to out1 (gather source) AND out2 (accumulator init = self-loop term).
template <int LAYER>
__global__ __launch_bounds__(256) void k_gemm(const float* __restrict__ in,
                                              const float* __restrict__ W,
                                              const float* __restrict__ dinv,
                                              const float* __restrict__ b1,
                                              const float* __restrict__ bnscale,
                                              const float* __restrict__ bnbias,
                                              float* __restrict__ out1,
                                              float* __restrict__ out2, int n) {
    __shared__ float ws[DF * DF];        // 36864 B
    __shared__ float xs[GROWS * PADX];   // 25600 B (pad 96->100 keeps b128 reads aligned+conflict-free)
    const int tid  = threadIdx.x;
    const int row0 = blockIdx.x * GROWS;

    for (int i = tid; i < DF * DF; i += 256) ws[i] = W[i];

    for (int i = tid; i < GROWS * DF; i += 256) {
        int r = i / DF, c = i - r * DF;
        int gr = row0 + r;
        float v = 0.0f;
        if (gr < n) {
            v = in[gr * DF + c];
            if (LAYER == 1) {
                float t = __builtin_fmaf(dinv[gr], v, b1[c]);
                t = (t >= 0.0f) ? t : SLOPE * t;
                v = __builtin_fmaf(t, bnscale[c], bnbias[c]);
            }
        }
        xs[r * PADX + c] = v;
    }
    __syncthreads();

    // 256 threads: cg = col-group (12 cols), rg = row-group (2 rows) -> 64x96 tile
    const int cg = tid & 7, rg = tid >> 3;
    const int c0 = cg * 12, r0 = rg * 2;

    float a0[12] = {};
    float a1[12] = {};

    for (int k = 0; k < DF; k += 4) {
        const float4 xa = *(const float4*)&xs[r0 * PADX + k];
        const float4 xb = *(const float4*)&xs[(r0 + 1) * PADX + k];
        const float xav[4] = {xa.x, xa.y, xa.z, xa.w};
        const float xbv[4] = {xb.x, xb.y, xb.z, xb.w};
#pragma unroll
        for (int kk = 0; kk < 4; ++kk) {
            const float4 w0 = *(const float4*)&ws[(k + kk) * DF + c0];
            const float4 w1 = *(const float4*)&ws[(k + kk) * DF + c0 + 4];
            const float4 w2 = *(const float4*)&ws[(k + kk) * DF + c0 + 8];
            const float wv[12] = {w0.x, w0.y, w0.z, w0.w, w1.x, w1.y,
                                  w1.z, w1.w, w2.x, w2.y, w2.z, w2.w};
#pragma unroll
            for (int j = 0; j < 12; ++j) {
                a0[j] = __builtin_fmaf(xav[kk], wv[j], a0[j]);
                a1[j] = __builtin_fmaf(xbv[kk], wv[j], a1[j]);
            }
        }
    }

    const int gr0 = row0 + r0;
    const int gr1 = gr0 + 1;
    if (gr0 < n) {
        const float dv = dinv[gr0];
        float4 o0 = make_float4(a0[0] * dv, a0[1] * dv, a0[2] * dv, a0[3] * dv);
        float4 o1 = make_float4(a0[4] * dv, a0[5] * dv, a0[6] * dv, a0[7] * dv);
        float4 o2 = make_float4(a0[8] * dv, a0[9] * dv, a0[10] * dv, a0[11] * dv);
        *(float4*)&out1[gr0 * DF + c0]     = o0;
        *(float4*)&out1[gr0 * DF + c0 + 4] = o1;
        *(float4*)&out1[gr0 * DF + c0 + 8] = o2;
        *(float4*)&out2[gr0 * DF + c0]     = o0;
        *(float4*)&out2[gr0 * DF + c0 + 4] = o1;
        *(float4*)&out2[gr0 * DF + c0 + 8] = o2;
    }
    if (gr1 < n) {
        const float dv = dinv[gr1];
        float4 o0 = make_float4(a1[0] * dv, a1[1] * dv, a1[2] * dv, a1[3] * dv);
        float4 o1 = make_float4(a1[4] * dv, a1[5] * dv, a1[6] * dv, a1[7] * dv);
        float4 o2 = make_float4(a1[8] * dv, a1[9] * dv, a1[10] * dv, a1[11] * dv);
        *(float4*)&out1[gr1 * DF + c0]     = o0;
        *(float4*)&out1[gr1 * DF + c0 + 4] = o1;
        *(float4*)&out1[gr1 * DF + c0 + 8] = o2;
        *(float4*)&out2[gr1 * DF + c0]     = o0;
        *(float4*)&out2[gr1 * DF + c0 + 4] = o1;
        *(float4*)&out2[gr1 * DF + c0 + 8] = o2;
    }
}

// ---------------- edge scatter: acc[dst] += hs[src] ----------------
__global__ __launch_bounds__(256) void k_scatter(const int* __restrict__ ei,
                                                 const float* __restrict__ hs,
                                                 float* __restrict__ acc, int E) {
    int g = blockIdx.x * 256 + threadIdx.x;
    int e = g / 24;
    if (e >= E) return;
    int q = g - e * 24;
    int src = ei[e];
    int dst = ei[E + e];
    const float4 v = *(const float4*)&hs[src * DF + q * 4];
    float* a = &acc[dst * DF + q * 4];
    atomicAdd(a + 0, v.x);
    atomicAdd(a + 1, v.y);
    atomicAdd(a + 2, v.z);
    atomicAdd(a + 3, v.w);
}

// ---------------- final epilogue: out = dinv[v]*acc2 + b2 ----------------
__global__ __launch_bounds__(256) void k_final(float* __restrict__ out,
                                               const float* __restrict__ dinv,
                                               const float* __restrict__ b2, int n) {
    int g = blockIdx.x * 256 + threadIdx.x;
    int v = g / 24;
    if (v >= n) return;
    int q = g - v * 24;
    float4 t = *(float4*)&out[v * DF + q * 4];
    const float4 b = *(const float4*)&b2[q * 4];
    const float dv = dinv[v];
    t.x = __builtin_fmaf(t.x, dv, b.x);
    t.y = __builtin_fmaf(t.y, dv, b.y);
    t.z = __builtin_fmaf(t.z, dv, b.z);
    t.w = __builtin_fmaf(t.w, dv, b.w);
    *(float4*)&out[v * DF + q * 4] = t;
}

extern "C" void kernel_launch(void* const* d_in, const int* in_sizes, int n_in,
                              void* d_out, int out_size, void* d_ws, size_t ws_size,
                              hipStream_t stream) {
    const float* node_feat = (const float*)d_in[0];
    const int*   ei        = (const int*)d_in[1];   // [2, E] row-major: src row then dst row
    const float* W1        = (const float*)d_in[2];
    const float* b1        = (const float*)d_in[3];
    const float* W2        = (const float*)d_in[4];
    const float* b2        = (const float*)d_in[5];
    const float* gamma     = (const float*)d_in[6];
    const float* beta      = (const float*)d_in[7];
    const float* mean      = (const float*)d_in[8];
    const float* var       = (const float*)d_in[9];

    const int n = in_sizes[0] / DF;   // 100000
    const int E = in_sizes[1] / 2;    // 800000

    // workspace layout (floats): deg[n], dinv[n], bnscale[96], bnbias[96], bufA[n*96], bufB[n*96]
    float* deg     = (float*)d_ws;
    float* dinv    = deg + n;
    float* bnscale = dinv + n;
    float* bnbias  = bnscale + DF;
    size_t head    = (size_t)(2 * n + 2 * DF + 31) & ~(size_t)31;
    float* bufA    = (float*)d_ws + head;
    float* bufB    = bufA + (size_t)n * DF;
    float* out     = (float*)d_out;

    k_init_deg<<<(n + 255) / 256, 256, 0, stream>>>(deg, n);
    k_bn<<<1, 128, 0, stream>>>(gamma, beta, mean, var, bnscale, bnbias);
    k_deg<<<(E + 255) / 256, 256, 0, stream>>>(ei, deg, E);
    k_dinv<<<(n + 255) / 256, 256, 0, stream>>>(deg, dinv, n);

    const int gblocks = (n + GROWS - 1) / GROWS;
    const int sblocks = (int)(((long long)E * 24 + 255) / 256);
    const int fblocks = (int)(((long long)n * 24 + 255) / 256);

    // layer 1: hs1 -> bufA (gather src), bufB (acc init = self-loop)
    k_gemm<0><<<gblocks, 256, 0, stream>>>(node_feat, W1, dinv, b1, bnscale, bnbias,
                                           bufA, bufB, n);
    k_scatter<<<sblocks, 256, 0, stream>>>(ei, bufA, bufB, E);

    // layer 2: input transform (dinv*acc1+b1 -> leaky -> bn) fused into GEMM load
    k_gemm<1><<<gblocks, 256, 0, stream>>>(bufB, W2, dinv, b1, bnscale, bnbias,
                                           bufA, out, n);
    k_scatter<<<sblocks, 256, 0, stream>>>(ei, bufA, out, E);

    k_final<<<fblocks, 256, 0, stream>>>(out, dinv, b2, n);
}

// Round 2
// 454.837 us; speedup vs baseline: 5.0733x; 5.0733x over previous
//
#include <hip/hip_runtime.h>

#define DF 96
#define GROWS 64
#define PADX 100
#define BN_EPS 1e-5f
#define SLOPE 0.05f
#define NPB 8           // nodes per gather block
#define GBLK (NPB * 24) // 192 threads

// ---------------- small prep kernels ----------------

__global__ __launch_bounds__(128) void k_bn(const float* __restrict__ gamma,
                                            const float* __restrict__ beta,
                                            const float* __restrict__ mean,
                                            const float* __restrict__ var,
                                            float* __restrict__ bnscale,
                                            float* __restrict__ bnbias) {
    int c = threadIdx.x;
    if (c < DF) {
        float s = gamma[c] * rsqrtf(var[c] + BN_EPS);
        bnscale[c] = s;
        bnbias[c]  = beta[c] - mean[c] * s;
    }
}

__global__ __launch_bounds__(256) void k_zero(int* __restrict__ cnt, int n) {
    int i = blockIdx.x * 256 + threadIdx.x;
    if (i < n) cnt[i] = 0;
}

__global__ __launch_bounds__(256) void k_count(const int* __restrict__ ei,
                                               int* __restrict__ cnt, int E) {
    int e = blockIdx.x * 256 + threadIdx.x;
    if (e < E) atomicAdd(&cnt[ei[E + e]], 1);  // dst row
}

// block-level exclusive scan of cnt -> rowptr (pre-offset), block totals -> bsum
__global__ __launch_bounds__(256) void k_scan1(const int* __restrict__ cnt,
                                               int* __restrict__ rowptr,
                                               int* __restrict__ bsum, int n) {
    __shared__ int sh[256];
    int t = threadIdx.x;
    int i = blockIdx.x * 256 + t;
    int x = (i < n) ? cnt[i] : 0;
    sh[t] = x;
    __syncthreads();
#pragma unroll
    for (int off = 1; off < 256; off <<= 1) {
        int v = (t >= off) ? sh[t - off] : 0;
        __syncthreads();
        sh[t] += v;
        __syncthreads();
    }
    if (i < n) rowptr[i] = sh[t] - x;       // exclusive, pre-offset
    if (t == 255) bsum[blockIdx.x] = sh[255];
}

// single-block exclusive scan of bsum in place (nb <= 512)
__global__ __launch_bounds__(512) void k_scan2(int* __restrict__ bsum, int nb) {
    __shared__ int sh[512];
    int t = threadIdx.x;
    int x = (t < nb) ? bsum[t] : 0;
    sh[t] = x;
    __syncthreads();
#pragma unroll
    for (int off = 1; off < 512; off <<= 1) {
        int v = (t >= off) ? sh[t - off] : 0;
        __syncthreads();
        sh[t] += v;
        __syncthreads();
    }
    if (t < nb) bsum[t] = sh[t] - x;        // exclusive
}

// finalize rowptr, init cursor (reuses cnt), compute dinv
__global__ __launch_bounds__(256) void k_scan3(int* __restrict__ rowptr,
                                               const int* __restrict__ bsum,
                                               int* __restrict__ cnt_cursor,
                                               float* __restrict__ dinv,
                                               int n, int E) {
    int i = blockIdx.x * 256 + threadIdx.x;
    if (i < n) {
        int c  = cnt_cursor[i];
        int rp = rowptr[i] + bsum[i >> 8];
        rowptr[i]     = rp;
        cnt_cursor[i] = rp;                    // cursor init
        dinv[i]       = rsqrtf((float)(c + 1)); // deg = in-edges + self-loop
    }
    if (i == 0) rowptr[n] = E;
}

__global__ __launch_bounds__(256) void k_fill(const int* __restrict__ ei,
                                              int* __restrict__ cursor,
                                              int* __restrict__ csr, int E) {
    int e = blockIdx.x * 256 + threadIdx.x;
    if (e < E) {
        int src = ei[e];
        int dst = ei[E + e];
        int pos = atomicAdd(&cursor[dst], 1);
        csr[pos] = src;
    }
}

// ---------------- GEMM: hs = transform(in) @ W * dinv[row] ----------------
// LAYER==0: transform = identity (in = node_feat)
// LAYER==1: transform = BN(LeakyReLU(dinv[row]*in + b1))   (in = agg1 raw sum)
template <int LAYER>
__global__ __launch_bounds__(256) void k_gemm(const float* __restrict__ in,
                                              const float* __restrict__ W,
                                              const float* __restrict__ dinv,
                                              const float* __restrict__ b1,
                                              const float* __restrict__ bnscale,
                                              const float* __restrict__ bnbias,
                                              float* __restrict__ out1, int n) {
    __shared__ float ws[DF * DF];
    __shared__ float xs[GROWS * PADX];
    const int tid  = threadIdx.x;
    const int row0 = blockIdx.x * GROWS;

    for (int i = tid; i < DF * DF; i += 256) ws[i] = W[i];

    for (int i = tid; i < GROWS * DF; i += 256) {
        int r = i / DF, c = i - r * DF;
        int gr = row0 + r;
        float v = 0.0f;
        if (gr < n) {
            v = in[gr * DF + c];
            if (LAYER == 1) {
                float t = __builtin_fmaf(dinv[gr], v, b1[c]);
                t = (t >= 0.0f) ? t : SLOPE * t;
                v = __builtin_fmaf(t, bnscale[c], bnbias[c]);
            }
        }
        xs[r * PADX + c] = v;
    }
    __syncthreads();

    const int cg = tid & 7, rg = tid >> 3;
    const int c0 = cg * 12, r0 = rg * 2;

    float a0[12] = {};
    float a1[12] = {};

    for (int k = 0; k < DF; k += 4) {
        const float4 xa = *(const float4*)&xs[r0 * PADX + k];
        const float4 xb = *(const float4*)&xs[(r0 + 1) * PADX + k];
        const float xav[4] = {xa.x, xa.y, xa.z, xa.w};
        const float xbv[4] = {xb.x, xb.y, xb.z, xb.w};
#pragma unroll
        for (int kk = 0; kk < 4; ++kk) {
            const float4 w0 = *(const float4*)&ws[(k + kk) * DF + c0];
            const float4 w1 = *(const float4*)&ws[(k + kk) * DF + c0 + 4];
            const float4 w2 = *(const float4*)&ws[(k + kk) * DF + c0 + 8];
            const float wv[12] = {w0.x, w0.y, w0.z, w0.w, w1.x, w1.y,
                                  w1.z, w1.w, w2.x, w2.y, w2.z, w2.w};
#pragma unroll
            for (int j = 0; j < 12; ++j) {
                a0[j] = __builtin_fmaf(xav[kk], wv[j], a0[j]);
                a1[j] = __builtin_fmaf(xbv[kk], wv[j], a1[j]);
            }
        }
    }

    const int gr0 = row0 + r0;
    const int gr1 = gr0 + 1;
    if (gr0 < n) {
        const float dv = dinv[gr0];
        *(float4*)&out1[gr0 * DF + c0]     = make_float4(a0[0]*dv, a0[1]*dv, a0[2]*dv, a0[3]*dv);
        *(float4*)&out1[gr0 * DF + c0 + 4] = make_float4(a0[4]*dv, a0[5]*dv, a0[6]*dv, a0[7]*dv);
        *(float4*)&out1[gr0 * DF + c0 + 8] = make_float4(a0[8]*dv, a0[9]*dv, a0[10]*dv, a0[11]*dv);
    }
    if (gr1 < n) {
        const float dv = dinv[gr1];
        *(float4*)&out1[gr1 * DF + c0]     = make_float4(a1[0]*dv, a1[1]*dv, a1[2]*dv, a1[3]*dv);
        *(float4*)&out1[gr1 * DF + c0 + 4] = make_float4(a1[4]*dv, a1[5]*dv, a1[6]*dv, a1[7]*dv);
        *(float4*)&out1[gr1 * DF + c0 + 8] = make_float4(a1[8]*dv, a1[9]*dv, a1[10]*dv, a1[11]*dv);
    }
}

// ---------------- CSR gather: out[v] = f( hs[v] + sum_{e in CSR[v]} hs[src] ) --
// LAYER==0: f = identity (raw sum -> agg buffer)
// LAYER==1: f = dinv[v]*sum + b2  (final output)
template <int LAYER>
__global__ __launch_bounds__(GBLK) void k_gather(const int* __restrict__ rowptr,
                                                 const int* __restrict__ csr,
                                                 const float* __restrict__ hs,
                                                 const float* __restrict__ dinv,
                                                 const float* __restrict__ b2,
                                                 float* __restrict__ outp, int n) {
    const int t = threadIdx.x;
    const int v = blockIdx.x * NPB + t / 24;
    const int q = t % 24;
    if (v >= n) return;

    float4 acc = *(const float4*)&hs[v * DF + q * 4];   // self-loop term
    const int e1 = rowptr[v + 1];
    for (int e = rowptr[v]; e < e1; ++e) {
        const int s = csr[e];
        const float4 m = *(const float4*)&hs[s * DF + q * 4];
        acc.x += m.x; acc.y += m.y; acc.z += m.z; acc.w += m.w;
    }

    if (LAYER == 0) {
        *(float4*)&outp[v * DF + q * 4] = acc;
    } else {
        const float dv = dinv[v];
        const float4 b = *(const float4*)&b2[q * 4];
        float4 o;
        o.x = __builtin_fmaf(acc.x, dv, b.x);
        o.y = __builtin_fmaf(acc.y, dv, b.y);
        o.z = __builtin_fmaf(acc.z, dv, b.z);
        o.w = __builtin_fmaf(acc.w, dv, b.w);
        *(float4*)&outp[v * DF + q * 4] = o;
    }
}

extern "C" void kernel_launch(void* const* d_in, const int* in_sizes, int n_in,
                              void* d_out, int out_size, void* d_ws, size_t ws_size,
                              hipStream_t stream) {
    const float* node_feat = (const float*)d_in[0];
    const int*   ei        = (const int*)d_in[1];
    const float* W1        = (const float*)d_in[2];
    const float* b1        = (const float*)d_in[3];
    const float* W2        = (const float*)d_in[4];
    const float* b2        = (const float*)d_in[5];
    const float* gamma     = (const float*)d_in[6];
    const float* beta      = (const float*)d_in[7];
    const float* mean      = (const float*)d_in[8];
    const float* var       = (const float*)d_in[9];

    const int n = in_sizes[0] / DF;   // 100000
    const int E = in_sizes[1] / 2;    // 800000
    const int nb = (n + 255) / 256;   // scan blocks (391 <= 512)

    // workspace layout
    char* base = (char*)d_ws;
    size_t off = 0;
    auto alloc = [&](size_t bytes) { void* p = base + off; off = (off + bytes + 15) & ~(size_t)15; return p; };
    int*   cnt     = (int*)alloc(sizeof(int) * n);        // later reused as cursor
    int*   rowptr  = (int*)alloc(sizeof(int) * (n + 1));
    int*   bsum    = (int*)alloc(sizeof(int) * 512);
    float* dinv    = (float*)alloc(sizeof(float) * n);
    float* bnscale = (float*)alloc(sizeof(float) * DF);
    float* bnbias  = (float*)alloc(sizeof(float) * DF);
    int*   csr     = (int*)alloc(sizeof(int) * E);
    float* bufA    = (float*)alloc(sizeof(float) * (size_t)n * DF); // hs1, then hs2
    float* bufB    = (float*)alloc(sizeof(float) * (size_t)n * DF); // agg1 raw sum
    float* out     = (float*)d_out;

    // ---- CSR build ----
    k_bn<<<1, 128, 0, stream>>>(gamma, beta, mean, var, bnscale, bnbias);
    k_zero<<<nb, 256, 0, stream>>>(cnt, n);
    k_count<<<(E + 255) / 256, 256, 0, stream>>>(ei, cnt, E);
    k_scan1<<<nb, 256, 0, stream>>>(cnt, rowptr, bsum, n);
    k_scan2<<<1, 512, 0, stream>>>(bsum, nb);
    k_scan3<<<nb, 256, 0, stream>>>(rowptr, bsum, cnt, dinv, n, E);
    k_fill<<<(E + 255) / 256, 256, 0, stream>>>(ei, cnt, csr, E);

    const int gblocks  = (n + GROWS - 1) / GROWS;
    const int gagather = (n + NPB - 1) / NPB;

    // layer 1
    k_gemm<0><<<gblocks, 256, 0, stream>>>(node_feat, W1, dinv, b1, bnscale, bnbias, bufA, n);
    k_gather<0><<<gagather, GBLK, 0, stream>>>(rowptr, csr, bufA, dinv, b2, bufB, n);

    // layer 2 (input transform fused into GEMM load; final epilogue fused into gather)
    k_gemm<1><<<gblocks, 256, 0, stream>>>(bufB, W2, dinv, b1, bnscale, bnbias, bufA, n);
    k_gather<1><<<gagather, GBLK, 0, stream>>>(rowptr, csr, bufA, dinv, b2, out, n);
}

// Round 3
// 361.320 us; speedup vs baseline: 6.3864x; 1.2588x over previous
//
#include <hip/hip_runtime.h>

#define DF 96
#define BN_EPS 1e-5f
#define SLOPE 0.05f
#define NPB 8           // nodes per gather block
#define GBLK (NPB * 24) // 192 threads

typedef __attribute__((ext_vector_type(8))) short bf16x8;
typedef __attribute__((ext_vector_type(4))) float f32x4;

__device__ __forceinline__ unsigned short f2bf(float f) {
    unsigned u = __builtin_bit_cast(unsigned, f);
    return (unsigned short)((u + 0x7FFFu + ((u >> 16) & 1u)) >> 16);
}

// ---------------- small prep kernels ----------------

__global__ __launch_bounds__(128) void k_bn(const float* __restrict__ gamma,
                                            const float* __restrict__ beta,
                                            const float* __restrict__ mean,
                                            const float* __restrict__ var,
                                            float* __restrict__ bnscale,
                                            float* __restrict__ bnbias) {
    int c = threadIdx.x;
    if (c < DF) {
        float s = gamma[c] * rsqrtf(var[c] + BN_EPS);
        bnscale[c] = s;
        bnbias[c]  = beta[c] - mean[c] * s;
    }
}

// Wt[n*96+k] = bf16(W[k*96+n]) for both weight matrices
__global__ __launch_bounds__(256) void k_wt(const float* __restrict__ W1,
                                            const float* __restrict__ W2,
                                            unsigned short* __restrict__ Wt1,
                                            unsigned short* __restrict__ Wt2) {
    int i = blockIdx.x * 256 + threadIdx.x;
    if (i < DF * DF) {
        int nn = i / DF, k = i - nn * DF;
        Wt1[i] = f2bf(W1[k * DF + nn]);
        Wt2[i] = f2bf(W2[k * DF + nn]);
    }
}

__global__ __launch_bounds__(256) void k_zero(int* __restrict__ cnt, int n) {
    int i = blockIdx.x * 256 + threadIdx.x;
    if (i < n) cnt[i] = 0;
}

__global__ __launch_bounds__(256) void k_count(const int* __restrict__ ei,
                                               int* __restrict__ cnt, int E) {
    int e = blockIdx.x * 256 + threadIdx.x;
    if (e < E) atomicAdd(&cnt[ei[E + e]], 1);  // dst row
}

__global__ __launch_bounds__(256) void k_scan1(const int* __restrict__ cnt,
                                               int* __restrict__ rowptr,
                                               int* __restrict__ bsum, int n) {
    __shared__ int sh[256];
    int t = threadIdx.x;
    int i = blockIdx.x * 256 + t;
    int x = (i < n) ? cnt[i] : 0;
    sh[t] = x;
    __syncthreads();
#pragma unroll
    for (int off = 1; off < 256; off <<= 1) {
        int v = (t >= off) ? sh[t - off] : 0;
        __syncthreads();
        sh[t] += v;
        __syncthreads();
    }
    if (i < n) rowptr[i] = sh[t] - x;
    if (t == 255) bsum[blockIdx.x] = sh[255];
}

__global__ __launch_bounds__(512) void k_scan2(int* __restrict__ bsum, int nb) {
    __shared__ int sh[512];
    int t = threadIdx.x;
    int x = (t < nb) ? bsum[t] : 0;
    sh[t] = x;
    __syncthreads();
#pragma unroll
    for (int off = 1; off < 512; off <<= 1) {
        int v = (t >= off) ? sh[t - off] : 0;
        __syncthreads();
        sh[t] += v;
        __syncthreads();
    }
    if (t < nb) bsum[t] = sh[t] - x;
}

__global__ __launch_bounds__(256) void k_scan3(int* __restrict__ rowptr,
                                               const int* __restrict__ bsum,
                                               int* __restrict__ cnt_cursor,
                                               float* __restrict__ dinv,
                                               int n, int E) {
    int i = blockIdx.x * 256 + threadIdx.x;
    if (i < n) {
        int c  = cnt_cursor[i];
        int rp = rowptr[i] + bsum[i >> 8];
        rowptr[i]     = rp;
        cnt_cursor[i] = rp;
        dinv[i]       = rsqrtf((float)(c + 1));
    }
    if (i == 0) rowptr[n] = E;
}

__global__ __launch_bounds__(256) void k_fill(const int* __restrict__ ei,
                                              int* __restrict__ cursor,
                                              int* __restrict__ csr, int E) {
    int e = blockIdx.x * 256 + threadIdx.x;
    if (e < E) {
        int src = ei[e];
        int dst = ei[E + e];
        int pos = atomicAdd(&cursor[dst], 1);
        csr[pos] = src;
    }
}

// ---------------- MFMA GEMM: hs = transform(in) @ W * dinv[row] ----------------
// No LDS. 4 waves/block, 16 rows/wave, full N=96 (6 n-tiles), K=96 (3 k-steps).
// B fragments (bf16 W^T) preloaded to registers; A loaded global->reg->bf16.
template <int LAYER>
__global__ __launch_bounds__(256) void k_gemm(const float* __restrict__ in,
                                              const unsigned short* __restrict__ Wt,
                                              const float* __restrict__ dinv,
                                              const float* __restrict__ b1,
                                              const float* __restrict__ bnscale,
                                              const float* __restrict__ bnbias,
                                              float* __restrict__ out1, int n) {
    const int tid  = threadIdx.x;
    const int wave = tid >> 6;
    const int lane = tid & 63;
    const int l16  = lane & 15;
    const int quad = lane >> 4;
    const int rowbase = blockIdx.x * 64 + wave * 16;
    const int m = rowbase + l16;
    const bool valid = (m < n);

    // B fragments: lane holds B[k=quad*8+j][n=nt*16+l16] = Wt[col][k..k+7]
    bf16x8 bfrag[6][3];
#pragma unroll
    for (int nt = 0; nt < 6; ++nt)
#pragma unroll
        for (int ks = 0; ks < 3; ++ks)
            bfrag[nt][ks] = *(const bf16x8*)&Wt[(nt * 16 + l16) * DF + ks * 32 + quad * 8];

    // A loads: pre-issue all 6 float4 loads (independent -> MLP)
    float4 ra[3][2];
    const float* rowp = in + (size_t)m * DF;
#pragma unroll
    for (int ks = 0; ks < 3; ++ks) {
        if (valid) {
            ra[ks][0] = *(const float4*)&rowp[ks * 32 + quad * 8];
            ra[ks][1] = *(const float4*)&rowp[ks * 32 + quad * 8 + 4];
        } else {
            ra[ks][0] = make_float4(0.f, 0.f, 0.f, 0.f);
            ra[ks][1] = make_float4(0.f, 0.f, 0.f, 0.f);
        }
    }

    if (LAYER == 1 && valid) {
        const float dv = dinv[m];
#pragma unroll
        for (int ks = 0; ks < 3; ++ks) {
            const int k0 = ks * 32 + quad * 8;
            const float4 c10 = *(const float4*)&b1[k0];
            const float4 c11 = *(const float4*)&b1[k0 + 4];
            const float4 s0  = *(const float4*)&bnscale[k0];
            const float4 s1  = *(const float4*)&bnscale[k0 + 4];
            const float4 d0  = *(const float4*)&bnbias[k0];
            const float4 d1  = *(const float4*)&bnbias[k0 + 4];
            float* a  = (float*)&ra[ks][0];
            const float* cb = (const float*)&c10;
            const float* sb = (const float*)&s0;
            const float* db = (const float*)&d0;
            // note: float4 pairs are contiguous in the arrays above only per-vector;
            // handle the two halves explicitly
            float* a1p = (float*)&ra[ks][1];
            const float* cb1 = (const float*)&c11;
            const float* sb1 = (const float*)&s1;
            const float* db1 = (const float*)&d1;
#pragma unroll
            for (int j = 0; j < 4; ++j) {
                float t = __builtin_fmaf(dv, a[j], cb[j]);
                t = (t >= 0.f) ? t : SLOPE * t;
                a[j] = __builtin_fmaf(t, sb[j], db[j]);
                float u = __builtin_fmaf(dv, a1p[j], cb1[j]);
                u = (u >= 0.f) ? u : SLOPE * u;
                a1p[j] = __builtin_fmaf(u, sb1[j], db1[j]);
            }
        }
    }

    // convert to bf16 A-fragments: lane holds A[m][k=quad*8+j]
    bf16x8 afrag[3];
#pragma unroll
    for (int ks = 0; ks < 3; ++ks) {
        const float* a0 = (const float*)&ra[ks][0];
        const float* a1 = (const float*)&ra[ks][1];
        bf16x8 f;
#pragma unroll
        for (int j = 0; j < 4; ++j) {
            f[j]     = (short)f2bf(a0[j]);
            f[j + 4] = (short)f2bf(a1[j]);
        }
        afrag[ks] = f;
    }

    f32x4 acc[6] = {};
#pragma unroll
    for (int ks = 0; ks < 3; ++ks)
#pragma unroll
        for (int nt = 0; nt < 6; ++nt)
            acc[nt] = __builtin_amdgcn_mfma_f32_16x16x32_bf16(afrag[ks], bfrag[nt][ks],
                                                              acc[nt], 0, 0, 0);

    // D layout: col = l16, row = quad*4 + reg
#pragma unroll
    for (int reg = 0; reg < 4; ++reg) {
        const int r = rowbase + quad * 4 + reg;
        if (r < n) {
            const float dv = dinv[r];
#pragma unroll
            for (int nt = 0; nt < 6; ++nt)
                out1[(size_t)r * DF + nt * 16 + l16] = acc[nt][reg] * dv;
        }
    }
}

// ---------------- CSR gather: out[v] = f( hs[v] + sum_{e} hs[csr[e]] ) ----------
template <int LAYER>
__global__ __launch_bounds__(GBLK) void k_gather(const int* __restrict__ rowptr,
                                                 const int* __restrict__ csr,
                                                 const float* __restrict__ hs,
                                                 const float* __restrict__ dinv,
                                                 const float* __restrict__ b2,
                                                 float* __restrict__ outp, int n) {
    const int t = threadIdx.x;
    const int v = blockIdx.x * NPB + t / 24;
    const int q = t % 24;
    if (v >= n) return;

    float4 acc = *(const float4*)&hs[(size_t)v * DF + q * 4];   // self-loop
    const int e0 = rowptr[v];
    const int e1 = rowptr[v + 1];
    int e = e0;
    for (; e + 4 <= e1; e += 4) {
        const int s0 = csr[e], s1 = csr[e + 1], s2 = csr[e + 2], s3 = csr[e + 3];
        const float4 m0 = *(const float4*)&hs[(size_t)s0 * DF + q * 4];
        const float4 m1 = *(const float4*)&hs[(size_t)s1 * DF + q * 4];
        const float4 m2 = *(const float4*)&hs[(size_t)s2 * DF + q * 4];
        const float4 m3 = *(const float4*)&hs[(size_t)s3 * DF + q * 4];
        acc.x += m0.x + m1.x + m2.x + m3.x;
        acc.y += m0.y + m1.y + m2.y + m3.y;
        acc.z += m0.z + m1.z + m2.z + m3.z;
        acc.w += m0.w + m1.w + m2.w + m3.w;
    }
    for (; e < e1; ++e) {
        const int s = csr[e];
        const float4 m = *(const float4*)&hs[(size_t)s * DF + q * 4];
        acc.x += m.x; acc.y += m.y; acc.z += m.z; acc.w += m.w;
    }

    if (LAYER == 0) {
        *(float4*)&outp[(size_t)v * DF + q * 4] = acc;
    } else {
        const float dv = dinv[v];
        const float4 b = *(const float4*)&b2[q * 4];
        float4 o;
        o.x = __builtin_fmaf(acc.x, dv, b.x);
        o.y = __builtin_fmaf(acc.y, dv, b.y);
        o.z = __builtin_fmaf(acc.z, dv, b.z);
        o.w = __builtin_fmaf(acc.w, dv, b.w);
        *(float4*)&outp[(size_t)v * DF + q * 4] = o;
    }
}

extern "C" void kernel_launch(void* const* d_in, const int* in_sizes, int n_in,
                              void* d_out, int out_size, void* d_ws, size_t ws_size,
                              hipStream_t stream) {
    const float* node_feat = (const float*)d_in[0];
    const int*   ei        = (const int*)d_in[1];
    const float* W1        = (const float*)d_in[2];
    const float* b1        = (const float*)d_in[3];
    const float* W2        = (const float*)d_in[4];
    const float* b2        = (const float*)d_in[5];
    const float* gamma     = (const float*)d_in[6];
    const float* beta      = (const float*)d_in[7];
    const float* mean      = (const float*)d_in[8];
    const float* var       = (const float*)d_in[9];

    const int n  = in_sizes[0] / DF;  // 100000
    const int E  = in_sizes[1] / 2;   // 800000
    const int nb = (n + 255) / 256;

    char* base = (char*)d_ws;
    size_t off = 0;
    auto alloc = [&](size_t bytes) { void* p = base + off; off = (off + bytes + 15) & ~(size_t)15; return p; };
    int*   cnt     = (int*)alloc(sizeof(int) * n);
    int*   rowptr  = (int*)alloc(sizeof(int) * (n + 1));
    int*   bsum    = (int*)alloc(sizeof(int) * 512);
    float* dinv    = (float*)alloc(sizeof(float) * n);
    float* bnscale = (float*)alloc(sizeof(float) * DF);
    float* bnbias  = (float*)alloc(sizeof(float) * DF);
    unsigned short* Wt1 = (unsigned short*)alloc(sizeof(short) * DF * DF);
    unsigned short* Wt2 = (unsigned short*)alloc(sizeof(short) * DF * DF);
    int*   csr     = (int*)alloc(sizeof(int) * E);
    float* bufA    = (float*)alloc(sizeof(float) * (size_t)n * DF);
    float* bufB    = (float*)alloc(sizeof(float) * (size_t)n * DF);
    float* out     = (float*)d_out;

    // prep + CSR build
    k_bn<<<1, 128, 0, stream>>>(gamma, beta, mean, var, bnscale, bnbias);
    k_wt<<<(DF * DF + 255) / 256, 256, 0, stream>>>(W1, W2, Wt1, Wt2);
    k_zero<<<nb, 256, 0, stream>>>(cnt, n);
    k_count<<<(E + 255) / 256, 256, 0, stream>>>(ei, cnt, E);
    k_scan1<<<nb, 256, 0, stream>>>(cnt, rowptr, bsum, n);
    k_scan2<<<1, 512, 0, stream>>>(bsum, nb);
    k_scan3<<<nb, 256, 0, stream>>>(rowptr, bsum, cnt, dinv, n, E);
    k_fill<<<(E + 255) / 256, 256, 0, stream>>>(ei, cnt, csr, E);

    const int gblocks  = (n + 63) / 64;
    const int gagather = (n + NPB - 1) / NPB;

    // layer 1
    k_gemm<0><<<gblocks, 256, 0, stream>>>(node_feat, Wt1, dinv, b1, bnscale, bnbias, bufA, n);
    k_gather<0><<<gagather, GBLK, 0, stream>>>(rowptr, csr, bufA, dinv, b2, bufB, n);

    // layer 2
    k_gemm<1><<<gblocks, 256, 0, stream>>>(bufB, Wt2, dinv, b1, bnscale, bnbias, bufA, n);
    k_gather<1><<<gagather, GBLK, 0, stream>>>(rowptr, csr, bufA, dinv, b2, out, n);
}

// Round 4
// 302.143 us; speedup vs baseline: 7.6372x; 1.1959x over previous
//
#include <hip/hip_runtime.h>

#define DF 96
#define BN_EPS 1e-5f
#define SLOPE 0.05f
#define NPB 8           // nodes per gather block
#define GBLK (NPB * 24) // 192 threads

typedef __attribute__((ext_vector_type(8))) short bf16x8;
typedef __attribute__((ext_vector_type(4))) float f32x4;
typedef __attribute__((ext_vector_type(4))) unsigned short u16x4;

__device__ __forceinline__ unsigned short f2bf(float f) {
    unsigned u = __builtin_bit_cast(unsigned, f);
    return (unsigned short)((u + 0x7FFFu + ((u >> 16) & 1u)) >> 16);
}
__device__ __forceinline__ float bf2f(unsigned short h) {
    return __builtin_bit_cast(float, (unsigned)h << 16);
}

// ---------------- fused prep: BN fold + weight transpose/convert + cnt zero ----
__global__ __launch_bounds__(256) void k_prep(const float* __restrict__ gamma,
                                              const float* __restrict__ beta,
                                              const float* __restrict__ mean,
                                              const float* __restrict__ var,
                                              float* __restrict__ bnscale,
                                              float* __restrict__ bnbias,
                                              const float* __restrict__ W1,
                                              const float* __restrict__ W2,
                                              unsigned short* __restrict__ Wt1,
                                              unsigned short* __restrict__ Wt2,
                                              int* __restrict__ cnt, int n) {
    int i = blockIdx.x * 256 + threadIdx.x;
    if (i < DF * DF) {
        int nn = i / DF, k = i - nn * DF;
        Wt1[i] = f2bf(W1[k * DF + nn]);
        Wt2[i] = f2bf(W2[k * DF + nn]);
    }
    if (i < DF) {
        float s = gamma[i] * rsqrtf(var[i] + BN_EPS);
        bnscale[i] = s;
        bnbias[i]  = beta[i] - mean[i] * s;
    }
    if (i < n) cnt[i] = 0;
}

__global__ __launch_bounds__(256) void k_count(const int* __restrict__ ei,
                                               int* __restrict__ cnt, int E) {
    int e = blockIdx.x * 256 + threadIdx.x;
    if (e < E) atomicAdd(&cnt[ei[E + e]], 1);  // dst row
}

__global__ __launch_bounds__(256) void k_scan1(const int* __restrict__ cnt,
                                               int* __restrict__ rowptr,
                                               int* __restrict__ bsum, int n) {
    __shared__ int sh[256];
    int t = threadIdx.x;
    int i = blockIdx.x * 256 + t;
    int x = (i < n) ? cnt[i] : 0;
    sh[t] = x;
    __syncthreads();
#pragma unroll
    for (int off = 1; off < 256; off <<= 1) {
        int v = (t >= off) ? sh[t - off] : 0;
        __syncthreads();
        sh[t] += v;
        __syncthreads();
    }
    if (i < n) rowptr[i] = sh[t] - x;
    if (t == 255) bsum[blockIdx.x] = sh[255];
}

__global__ __launch_bounds__(512) void k_scan2(int* __restrict__ bsum, int nb) {
    __shared__ int sh[512];
    int t = threadIdx.x;
    int x = (t < nb) ? bsum[t] : 0;
    sh[t] = x;
    __syncthreads();
#pragma unroll
    for (int off = 1; off < 512; off <<= 1) {
        int v = (t >= off) ? sh[t - off] : 0;
        __syncthreads();
        sh[t] += v;
        __syncthreads();
    }
    if (t < nb) bsum[t] = sh[t] - x;
}

__global__ __launch_bounds__(256) void k_scan3(int* __restrict__ rowptr,
                                               const int* __restrict__ bsum,
                                               int* __restrict__ cnt_cursor,
                                               float* __restrict__ dinv,
                                               int n, int E) {
    int i = blockIdx.x * 256 + threadIdx.x;
    if (i < n) {
        int c  = cnt_cursor[i];
        int rp = rowptr[i] + bsum[i >> 8];
        rowptr[i]     = rp;
        cnt_cursor[i] = rp;
        dinv[i]       = rsqrtf((float)(c + 1));
    }
    if (i == 0) rowptr[n] = E;
}

__global__ __launch_bounds__(256) void k_fill(const int* __restrict__ ei,
                                              int* __restrict__ cursor,
                                              int* __restrict__ csr, int E) {
    int e = blockIdx.x * 256 + threadIdx.x;
    if (e < E) {
        int src = ei[e];
        int dst = ei[E + e];
        int pos = atomicAdd(&cursor[dst], 1);
        csr[pos] = src;
    }
}

// ---------------- MFMA GEMM: hs(bf16) = in @ W * dinv[row] ----------------
// LAYER 0: in = fp32 node_feat.  LAYER 1: in = bf16 pre-transformed x2.
// No LDS, no barriers. 4 waves/block, 16 rows/wave, N=96 (6 tiles), K=96 (3 steps).
template <int LAYER>
__global__ __launch_bounds__(256) void k_gemm(const void* __restrict__ in_,
                                              const unsigned short* __restrict__ Wt,
                                              const float* __restrict__ dinv,
                                              unsigned short* __restrict__ outb, int n) {
    const int tid  = threadIdx.x;
    const int wave = tid >> 6;
    const int lane = tid & 63;
    const int l16  = lane & 15;
    const int quad = lane >> 4;
    const int rowbase = blockIdx.x * 64 + wave * 16;
    const int m = rowbase + l16;
    const bool valid = (m < n);

    // B fragments: lane holds B[k=quad*8+j][n=nt*16+l16] = Wt[col][k..k+7]
    bf16x8 bfrag[6][3];
#pragma unroll
    for (int nt = 0; nt < 6; ++nt)
#pragma unroll
        for (int ks = 0; ks < 3; ++ks)
            bfrag[nt][ks] = *(const bf16x8*)&Wt[(nt * 16 + l16) * DF + ks * 32 + quad * 8];

    bf16x8 afrag[3];
    const bf16x8 zf = {};
    if (LAYER == 0) {
        const float* in = (const float*)in_;
        const float* rowp = in + (size_t)m * DF;
        float4 ra[3][2];
#pragma unroll
        for (int ks = 0; ks < 3; ++ks) {
            if (valid) {
                ra[ks][0] = *(const float4*)&rowp[ks * 32 + quad * 8];
                ra[ks][1] = *(const float4*)&rowp[ks * 32 + quad * 8 + 4];
            } else {
                ra[ks][0] = make_float4(0.f, 0.f, 0.f, 0.f);
                ra[ks][1] = make_float4(0.f, 0.f, 0.f, 0.f);
            }
        }
#pragma unroll
        for (int ks = 0; ks < 3; ++ks) {
            const float* a0 = (const float*)&ra[ks][0];
            const float* a1 = (const float*)&ra[ks][1];
            bf16x8 f;
#pragma unroll
            for (int j = 0; j < 4; ++j) {
                f[j]     = (short)f2bf(a0[j]);
                f[j + 4] = (short)f2bf(a1[j]);
            }
            afrag[ks] = f;
        }
    } else {
        const unsigned short* in = (const unsigned short*)in_;
#pragma unroll
        for (int ks = 0; ks < 3; ++ks)
            afrag[ks] = valid ? *(const bf16x8*)&in[(size_t)m * DF + ks * 32 + quad * 8] : zf;
    }

    f32x4 acc[6] = {};
#pragma unroll
    for (int ks = 0; ks < 3; ++ks)
#pragma unroll
        for (int nt = 0; nt < 6; ++nt)
            acc[nt] = __builtin_amdgcn_mfma_f32_16x16x32_bf16(afrag[ks], bfrag[nt][ks],
                                                              acc[nt], 0, 0, 0);

    // D layout: col = l16, row = quad*4 + reg.  Store bf16 with dinv row-scale.
#pragma unroll
    for (int reg = 0; reg < 4; ++reg) {
        const int r = rowbase + quad * 4 + reg;
        if (r < n) {
            const float dv = dinv[r];
#pragma unroll
            for (int nt = 0; nt < 6; ++nt)
                outb[(size_t)r * DF + nt * 16 + l16] = f2bf(acc[nt][reg] * dv);
        }
    }
}

// ---------------- CSR gather over bf16 rows ----------------
// LAYER 0: out(bf16) = BN(LeakyReLU(dinv[v]*(self+sum) + b1))   (feeds GEMM2)
// LAYER 1: out(fp32) = dinv[v]*(self+sum) + b2                  (final output)
template <int LAYER>
__global__ __launch_bounds__(GBLK) void k_gather(const int* __restrict__ rowptr,
                                                 const int* __restrict__ csr,
                                                 const unsigned short* __restrict__ hs,
                                                 const float* __restrict__ dinv,
                                                 const float* __restrict__ b1,
                                                 const float* __restrict__ bnscale,
                                                 const float* __restrict__ bnbias,
                                                 const float* __restrict__ b2,
                                                 void* __restrict__ outp, int n) {
    const int t = threadIdx.x;
    const int v = blockIdx.x * NPB + t / 24;
    const int q = t % 24;
    if (v >= n) return;

    const u16x4 h0 = *(const u16x4*)&hs[(size_t)v * DF + q * 4];  // self-loop
    float4 acc = make_float4(bf2f(h0[0]), bf2f(h0[1]), bf2f(h0[2]), bf2f(h0[3]));

    const int e0 = rowptr[v];
    const int e1 = rowptr[v + 1];
    int e = e0;
    for (; e + 4 <= e1; e += 4) {
        const int s0 = csr[e], s1 = csr[e + 1], s2 = csr[e + 2], s3 = csr[e + 3];
        const u16x4 m0 = *(const u16x4*)&hs[(size_t)s0 * DF + q * 4];
        const u16x4 m1 = *(const u16x4*)&hs[(size_t)s1 * DF + q * 4];
        const u16x4 m2 = *(const u16x4*)&hs[(size_t)s2 * DF + q * 4];
        const u16x4 m3 = *(const u16x4*)&hs[(size_t)s3 * DF + q * 4];
        acc.x += bf2f(m0[0]) + bf2f(m1[0]) + bf2f(m2[0]) + bf2f(m3[0]);
        acc.y += bf2f(m0[1]) + bf2f(m1[1]) + bf2f(m2[1]) + bf2f(m3[1]);
        acc.z += bf2f(m0[2]) + bf2f(m1[2]) + bf2f(m2[2]) + bf2f(m3[2]);
        acc.w += bf2f(m0[3]) + bf2f(m1[3]) + bf2f(m2[3]) + bf2f(m3[3]);
    }
    for (; e < e1; ++e) {
        const int s = csr[e];
        const u16x4 m = *(const u16x4*)&hs[(size_t)s * DF + q * 4];
        acc.x += bf2f(m[0]); acc.y += bf2f(m[1]);
        acc.z += bf2f(m[2]); acc.w += bf2f(m[3]);
    }

    const float dv = dinv[v];
    if (LAYER == 0) {
        const float4 c = *(const float4*)&b1[q * 4];
        const float4 s = *(const float4*)&bnscale[q * 4];
        const float4 d = *(const float4*)&bnbias[q * 4];
        float tx = __builtin_fmaf(dv, acc.x, c.x);
        float ty = __builtin_fmaf(dv, acc.y, c.y);
        float tz = __builtin_fmaf(dv, acc.z, c.z);
        float tw = __builtin_fmaf(dv, acc.w, c.w);
        tx = (tx >= 0.f) ? tx : SLOPE * tx;
        ty = (ty >= 0.f) ? ty : SLOPE * ty;
        tz = (tz >= 0.f) ? tz : SLOPE * tz;
        tw = (tw >= 0.f) ? tw : SLOPE * tw;
        u16x4 o;
        o[0] = f2bf(__builtin_fmaf(tx, s.x, d.x));
        o[1] = f2bf(__builtin_fmaf(ty, s.y, d.y));
        o[2] = f2bf(__builtin_fmaf(tz, s.z, d.z));
        o[3] = f2bf(__builtin_fmaf(tw, s.w, d.w));
        *(u16x4*)((unsigned short*)outp + (size_t)v * DF + q * 4) = o;
    } else {
        const float4 b = *(const float4*)&b2[q * 4];
        float4 o;
        o.x = __builtin_fmaf(acc.x, dv, b.x);
        o.y = __builtin_fmaf(acc.y, dv, b.y);
        o.z = __builtin_fmaf(acc.z, dv, b.z);
        o.w = __builtin_fmaf(acc.w, dv, b.w);
        *(float4*)((float*)outp + (size_t)v * DF + q * 4) = o;
    }
}

extern "C" void kernel_launch(void* const* d_in, const int* in_sizes, int n_in,
                              void* d_out, int out_size, void* d_ws, size_t ws_size,
                              hipStream_t stream) {
    const float* node_feat = (const float*)d_in[0];
    const int*   ei        = (const int*)d_in[1];
    const float* W1        = (const float*)d_in[2];
    const float* b1        = (const float*)d_in[3];
    const float* W2        = (const float*)d_in[4];
    const float* b2        = (const float*)d_in[5];
    const float* gamma     = (const float*)d_in[6];
    const float* beta      = (const float*)d_in[7];
    const float* mean      = (const float*)d_in[8];
    const float* var       = (const float*)d_in[9];

    const int n  = in_sizes[0] / DF;  // 100000
    const int E  = in_sizes[1] / 2;   // 800000
    const int nb = (n + 255) / 256;

    char* base = (char*)d_ws;
    size_t off = 0;
    auto alloc = [&](size_t bytes) { void* p = base + off; off = (off + bytes + 15) & ~(size_t)15; return p; };
    int*   cnt     = (int*)alloc(sizeof(int) * n);
    int*   rowptr  = (int*)alloc(sizeof(int) * (n + 1));
    int*   bsum    = (int*)alloc(sizeof(int) * 512);
    float* dinv    = (float*)alloc(sizeof(float) * n);
    float* bnscale = (float*)alloc(sizeof(float) * DF);
    float* bnbias  = (float*)alloc(sizeof(float) * DF);
    unsigned short* Wt1 = (unsigned short*)alloc(sizeof(short) * DF * DF);
    unsigned short* Wt2 = (unsigned short*)alloc(sizeof(short) * DF * DF);
    int*   csr     = (int*)alloc(sizeof(int) * E);
    unsigned short* bufA = (unsigned short*)alloc(sizeof(short) * (size_t)n * DF); // hs1, hs2
    unsigned short* bufB = (unsigned short*)alloc(sizeof(short) * (size_t)n * DF); // x2
    float* out     = (float*)d_out;

    // prep + CSR build
    k_prep<<<nb, 256, 0, stream>>>(gamma, beta, mean, var, bnscale, bnbias,
                                   W1, W2, Wt1, Wt2, cnt, n);
    k_count<<<(E + 255) / 256, 256, 0, stream>>>(ei, cnt, E);
    k_scan1<<<nb, 256, 0, stream>>>(cnt, rowptr, bsum, n);
    k_scan2<<<1, 512, 0, stream>>>(bsum, nb);
    k_scan3<<<nb, 256, 0, stream>>>(rowptr, bsum, cnt, dinv, n, E);
    k_fill<<<(E + 255) / 256, 256, 0, stream>>>(ei, cnt, csr, E);

    const int gblocks  = (n + 63) / 64;
    const int gagather = (n + NPB - 1) / NPB;

    // layer 1
    k_gemm<0><<<gblocks, 256, 0, stream>>>(node_feat, Wt1, dinv, bufA, n);
    k_gather<0><<<gagather, GBLK, 0, stream>>>(rowptr, csr, bufA, dinv, b1, bnscale,
                                               bnbias, b2, bufB, n);
    // layer 2
    k_gemm<1><<<gblocks, 256, 0, stream>>>(bufB, Wt2, dinv, bufA, n);
    k_gather<1><<<gagather, GBLK, 0, stream>>>(rowptr, csr, bufA, dinv, b1, bnscale,
                                               bnbias, b2, out, n);
}

// Round 5
// 266.332 us; speedup vs baseline: 8.6641x; 1.1345x over previous
//
#include <hip/hip_runtime.h>

#define DF 96
#define BN_EPS 1e-5f
#define SLOPE 0.05f
#define NPB 8           // nodes per gather block
#define GBLK (NPB * 24) // 192 threads

typedef __attribute__((ext_vector_type(8))) short bf16x8;
typedef __attribute__((ext_vector_type(4))) float f32x4;
typedef __attribute__((ext_vector_type(4))) unsigned short u16x4;

__device__ __forceinline__ unsigned short f2bf(float f) {
    unsigned u = __builtin_bit_cast(unsigned, f);
    return (unsigned short)((u + 0x7FFFu + ((u >> 16) & 1u)) >> 16);
}
__device__ __forceinline__ float bf2f(unsigned short h) {
    return __builtin_bit_cast(float, (unsigned)h << 16);
}

// ---------------- fused prep: BN fold + weight transpose/convert + cnt zero ----
__global__ __launch_bounds__(256) void k_prep(const float* __restrict__ gamma,
                                              const float* __restrict__ beta,
                                              const float* __restrict__ mean,
                                              const float* __restrict__ var,
                                              float* __restrict__ bnscale,
                                              float* __restrict__ bnbias,
                                              const float* __restrict__ W1,
                                              const float* __restrict__ W2,
                                              unsigned short* __restrict__ Wt1,
                                              unsigned short* __restrict__ Wt2,
                                              int* __restrict__ cnt, int n) {
    int i = blockIdx.x * 256 + threadIdx.x;
    if (i < DF * DF) {
        int nn = i / DF, k = i - nn * DF;
        Wt1[i] = f2bf(W1[k * DF + nn]);
        Wt2[i] = f2bf(W2[k * DF + nn]);
    }
    if (i < DF) {
        float s = gamma[i] * rsqrtf(var[i] + BN_EPS);
        bnscale[i] = s;
        bnbias[i]  = beta[i] - mean[i] * s;
    }
    if (i < n) cnt[i] = 0;
}

// count in-degree AND record each edge's rank within its dst bucket
__global__ __launch_bounds__(256) void k_countrank(const int* __restrict__ ei,
                                                   int* __restrict__ cnt,
                                                   int* __restrict__ rank, int E) {
    int e = blockIdx.x * 256 + threadIdx.x;
    if (e < E) rank[e] = atomicAdd(&cnt[ei[E + e]], 1);
}

// per-256-chunk exclusive scan of cnt -> rowptr (pre-offset), chunk totals -> bsum
__global__ __launch_bounds__(256) void k_scan1(const int* __restrict__ cnt,
                                               int* __restrict__ rowptr,
                                               int* __restrict__ bsum, int n) {
    __shared__ int sh[256];
    int t = threadIdx.x;
    int i = blockIdx.x * 256 + t;
    int x = (i < n) ? cnt[i] : 0;
    sh[t] = x;
    __syncthreads();
#pragma unroll
    for (int off = 1; off < 256; off <<= 1) {
        int v = (t >= off) ? sh[t - off] : 0;
        __syncthreads();
        sh[t] += v;
        __syncthreads();
    }
    if (i < n) rowptr[i] = sh[t] - x;
    if (t == 255) bsum[blockIdx.x] = sh[255];
}

// every block redundantly scans bsum in LDS, then finalizes rowptr + dinv
__global__ __launch_bounds__(512) void k_scan23(int* __restrict__ rowptr,
                                                const int* __restrict__ bsum,
                                                const int* __restrict__ cnt,
                                                float* __restrict__ dinv,
                                                int n, int E, int nb) {
    __shared__ int sh[512];
    __shared__ int sbex[512];
    const int t = threadIdx.x;
    int x = (t < nb) ? bsum[t] : 0;
    sh[t] = x;
    __syncthreads();
#pragma unroll
    for (int off = 1; off < 512; off <<= 1) {
        int v = (t >= off) ? sh[t - off] : 0;
        __syncthreads();
        sh[t] += v;
        __syncthreads();
    }
    sbex[t] = sh[t] - x;   // exclusive chunk offsets
    __syncthreads();

    const int i = blockIdx.x * 512 + t;
    if (i < n) {
        rowptr[i] = rowptr[i] + sbex[i >> 8];
        dinv[i]   = rsqrtf((float)cnt[i] + 1.0f);
    }
    if (i == 0) rowptr[n] = E;
}

// atomic-free CSR fill: position = rowptr[dst] + rank[e]
__global__ __launch_bounds__(256) void k_fill(const int* __restrict__ ei,
                                              const int* __restrict__ rowptr,
                                              const int* __restrict__ rank,
                                              int* __restrict__ csr, int E) {
    int e = blockIdx.x * 256 + threadIdx.x;
    if (e < E) {
        int src = ei[e];
        int dst = ei[E + e];
        csr[rowptr[dst] + rank[e]] = src;
    }
}

// ---------------- MFMA GEMM: hs(bf16) = in @ W * dinv[row] ----------------
// LAYER 0: in = fp32 node_feat.  LAYER 1: in = bf16 pre-transformed x2.
// No LDS, no barriers. 4 waves/block, 16 rows/wave, N=96 (6 tiles), K=96 (3 steps).
template <int LAYER>
__global__ __launch_bounds__(256) void k_gemm(const void* __restrict__ in_,
                                              const unsigned short* __restrict__ Wt,
                                              const float* __restrict__ dinv,
                                              unsigned short* __restrict__ outb, int n) {
    const int tid  = threadIdx.x;
    const int wave = tid >> 6;
    const int lane = tid & 63;
    const int l16  = lane & 15;
    const int quad = lane >> 4;
    const int rowbase = blockIdx.x * 64 + wave * 16;
    const int m = rowbase + l16;
    const bool valid = (m < n);

    // B fragments: lane holds B[k=quad*8+j][n=nt*16+l16] = Wt[col][k..k+7]
    bf16x8 bfrag[6][3];
#pragma unroll
    for (int nt = 0; nt < 6; ++nt)
#pragma unroll
        for (int ks = 0; ks < 3; ++ks)
            bfrag[nt][ks] = *(const bf16x8*)&Wt[(nt * 16 + l16) * DF + ks * 32 + quad * 8];

    bf16x8 afrag[3];
    const bf16x8 zf = {};
    if (LAYER == 0) {
        const float* in = (const float*)in_;
        const float* rowp = in + (size_t)m * DF;
        float4 ra[3][2];
#pragma unroll
        for (int ks = 0; ks < 3; ++ks) {
            if (valid) {
                ra[ks][0] = *(const float4*)&rowp[ks * 32 + quad * 8];
                ra[ks][1] = *(const float4*)&rowp[ks * 32 + quad * 8 + 4];
            } else {
                ra[ks][0] = make_float4(0.f, 0.f, 0.f, 0.f);
                ra[ks][1] = make_float4(0.f, 0.f, 0.f, 0.f);
            }
        }
#pragma unroll
        for (int ks = 0; ks < 3; ++ks) {
            const float* a0 = (const float*)&ra[ks][0];
            const float* a1 = (const float*)&ra[ks][1];
            bf16x8 f;
#pragma unroll
            for (int j = 0; j < 4; ++j) {
                f[j]     = (short)f2bf(a0[j]);
                f[j + 4] = (short)f2bf(a1[j]);
            }
            afrag[ks] = f;
        }
    } else {
        const unsigned short* in = (const unsigned short*)in_;
#pragma unroll
        for (int ks = 0; ks < 3; ++ks)
            afrag[ks] = valid ? *(const bf16x8*)&in[(size_t)m * DF + ks * 32 + quad * 8] : zf;
    }

    f32x4 acc[6] = {};
#pragma unroll
    for (int ks = 0; ks < 3; ++ks)
#pragma unroll
        for (int nt = 0; nt < 6; ++nt)
            acc[nt] = __builtin_amdgcn_mfma_f32_16x16x32_bf16(afrag[ks], bfrag[nt][ks],
                                                              acc[nt], 0, 0, 0);

    // D layout: col = l16, row = quad*4 + reg.  Store bf16 with dinv row-scale.
#pragma unroll
    for (int reg = 0; reg < 4; ++reg) {
        const int r = rowbase + quad * 4 + reg;
        if (r < n) {
            const float dv = dinv[r];
#pragma unroll
            for (int nt = 0; nt < 6; ++nt)
                outb[(size_t)r * DF + nt * 16 + l16] = f2bf(acc[nt][reg] * dv);
        }
    }
}

// ---------------- CSR gather over bf16 rows ----------------
// LAYER 0: out(bf16) = BN(LeakyReLU(dinv[v]*(self+sum) + b1))   (feeds GEMM2)
// LAYER 1: out(fp32) = dinv[v]*(self+sum) + b2                  (final output)
template <int LAYER>
__global__ __launch_bounds__(GBLK) void k_gather(const int* __restrict__ rowptr,
                                                 const int* __restrict__ csr,
                                                 const unsigned short* __restrict__ hs,
                                                 const float* __restrict__ dinv,
                                                 const float* __restrict__ b1,
                                                 const float* __restrict__ bnscale,
                                                 const float* __restrict__ bnbias,
                                                 const float* __restrict__ b2,
                                                 void* __restrict__ outp, int n) {
    const int t = threadIdx.x;
    const int v = blockIdx.x * NPB + t / 24;
    const int q = t % 24;
    if (v >= n) return;

    const u16x4 h0 = *(const u16x4*)&hs[(size_t)v * DF + q * 4];  // self-loop
    float4 acc = make_float4(bf2f(h0[0]), bf2f(h0[1]), bf2f(h0[2]), bf2f(h0[3]));

    const int e0 = rowptr[v];
    const int e1 = rowptr[v + 1];
    int e = e0;
    for (; e + 4 <= e1; e += 4) {
        const int s0 = csr[e], s1 = csr[e + 1], s2 = csr[e + 2], s3 = csr[e + 3];
        const u16x4 m0 = *(const u16x4*)&hs[(size_t)s0 * DF + q * 4];
        const u16x4 m1 = *(const u16x4*)&hs[(size_t)s1 * DF + q * 4];
        const u16x4 m2 = *(const u16x4*)&hs[(size_t)s2 * DF + q * 4];
        const u16x4 m3 = *(const u16x4*)&hs[(size_t)s3 * DF + q * 4];
        acc.x += bf2f(m0[0]) + bf2f(m1[0]) + bf2f(m2[0]) + bf2f(m3[0]);
        acc.y += bf2f(m0[1]) + bf2f(m1[1]) + bf2f(m2[1]) + bf2f(m3[1]);
        acc.z += bf2f(m0[2]) + bf2f(m1[2]) + bf2f(m2[2]) + bf2f(m3[2]);
        acc.w += bf2f(m0[3]) + bf2f(m1[3]) + bf2f(m2[3]) + bf2f(m3[3]);
    }
    for (; e < e1; ++e) {
        const int s = csr[e];
        const u16x4 m = *(const u16x4*)&hs[(size_t)s * DF + q * 4];
        acc.x += bf2f(m[0]); acc.y += bf2f(m[1]);
        acc.z += bf2f(m[2]); acc.w += bf2f(m[3]);
    }

    const float dv = dinv[v];
    if (LAYER == 0) {
        const float4 c = *(const float4*)&b1[q * 4];
        const float4 s = *(const float4*)&bnscale[q * 4];
        const float4 d = *(const float4*)&bnbias[q * 4];
        float tx = __builtin_fmaf(dv, acc.x, c.x);
        float ty = __builtin_fmaf(dv, acc.y, c.y);
        float tz = __builtin_fmaf(dv, acc.z, c.z);
        float tw = __builtin_fmaf(dv, acc.w, c.w);
        tx = (tx >= 0.f) ? tx : SLOPE * tx;
        ty = (ty >= 0.f) ? ty : SLOPE * ty;
        tz = (tz >= 0.f) ? tz : SLOPE * tz;
        tw = (tw >= 0.f) ? tw : SLOPE * tw;
        u16x4 o;
        o[0] = f2bf(__builtin_fmaf(tx, s.x, d.x));
        o[1] = f2bf(__builtin_fmaf(ty, s.y, d.y));
        o[2] = f2bf(__builtin_fmaf(tz, s.z, d.z));
        o[3] = f2bf(__builtin_fmaf(tw, s.w, d.w));
        *(u16x4*)((unsigned short*)outp + (size_t)v * DF + q * 4) = o;
    } else {
        const float4 b = *(const float4*)&b2[q * 4];
        float4 o;
        o.x = __builtin_fmaf(acc.x, dv, b.x);
        o.y = __builtin_fmaf(acc.y, dv, b.y);
        o.z = __builtin_fmaf(acc.z, dv, b.z);
        o.w = __builtin_fmaf(acc.w, dv, b.w);
        *(float4*)((float*)outp + (size_t)v * DF + q * 4) = o;
    }
}

extern "C" void kernel_launch(void* const* d_in, const int* in_sizes, int n_in,
                              void* d_out, int out_size, void* d_ws, size_t ws_size,
                              hipStream_t stream) {
    const float* node_feat = (const float*)d_in[0];
    const int*   ei        = (const int*)d_in[1];
    const float* W1        = (const float*)d_in[2];
    const float* b1        = (const float*)d_in[3];
    const float* W2        = (const float*)d_in[4];
    const float* b2        = (const float*)d_in[5];
    const float* gamma     = (const float*)d_in[6];
    const float* beta      = (const float*)d_in[7];
    const float* mean      = (const float*)d_in[8];
    const float* var       = (const float*)d_in[9];

    const int n  = in_sizes[0] / DF;  // 100000
    const int E  = in_sizes[1] / 2;   // 800000
    const int nb = (n + 255) / 256;   // 391

    char* base = (char*)d_ws;
    size_t off = 0;
    auto alloc = [&](size_t bytes) { void* p = base + off; off = (off + bytes + 15) & ~(size_t)15; return p; };
    int*   cnt     = (int*)alloc(sizeof(int) * n);
    int*   rowptr  = (int*)alloc(sizeof(int) * (n + 1));
    int*   bsum    = (int*)alloc(sizeof(int) * 512);
    float* dinv    = (float*)alloc(sizeof(float) * n);
    float* bnscale = (float*)alloc(sizeof(float) * DF);
    float* bnbias  = (float*)alloc(sizeof(float) * DF);
    unsigned short* Wt1 = (unsigned short*)alloc(sizeof(short) * DF * DF);
    unsigned short* Wt2 = (unsigned short*)alloc(sizeof(short) * DF * DF);
    int*   rank    = (int*)alloc(sizeof(int) * E);
    int*   csr     = (int*)alloc(sizeof(int) * E);
    unsigned short* bufA = (unsigned short*)alloc(sizeof(short) * (size_t)n * DF); // hs1, hs2
    unsigned short* bufB = (unsigned short*)alloc(sizeof(short) * (size_t)n * DF); // x2
    float* out     = (float*)d_out;

    // prep + CSR build
    k_prep<<<nb, 256, 0, stream>>>(gamma, beta, mean, var, bnscale, bnbias,
                                   W1, W2, Wt1, Wt2, cnt, n);
    k_countrank<<<(E + 255) / 256, 256, 0, stream>>>(ei, cnt, rank, E);
    k_scan1<<<nb, 256, 0, stream>>>(cnt, rowptr, bsum, n);
    k_scan23<<<(n + 511) / 512, 512, 0, stream>>>(rowptr, bsum, cnt, dinv, n, E, nb);
    k_fill<<<(E + 255) / 256, 256, 0, stream>>>(ei, rowptr, rank, csr, E);

    const int gblocks  = (n + 63) / 64;
    const int gagather = (n + NPB - 1) / NPB;

    // layer 1
    k_gemm<0><<<gblocks, 256, 0, stream>>>(node_feat, Wt1, dinv, bufA, n);
    k_gather<0><<<gagather, GBLK, 0, stream>>>(rowptr, csr, bufA, dinv, b1, bnscale,
                                               bnbias, b2, bufB, n);
    // layer 2
    k_gemm<1><<<gblocks, 256, 0, stream>>>(bufB, Wt2, dinv, bufA, n);
    k_gather<1><<<gagather, GBLK, 0, stream>>>(rowptr, csr, bufA, dinv, b1, bnscale,
                                               bnbias, b2, out, n);
}

// Round 6
// 265.506 us; speedup vs baseline: 8.6910x; 1.0031x over previous
//
#include <hip/hip_runtime.h>

#define DF 96
#define BN_EPS 1e-5f
#define SLOPE 0.05f
#define LPN 12            // lanes per node in gather
#define GBLK 192          // gather block threads
#define NPBG (GBLK / LPN) // 16 nodes per gather block

typedef __attribute__((ext_vector_type(8))) short bf16x8;
typedef __attribute__((ext_vector_type(4))) float f32x4;
typedef __attribute__((ext_vector_type(4))) unsigned short u16x4;
typedef __attribute__((ext_vector_type(8))) unsigned short u16x8;

__device__ __forceinline__ unsigned short f2bf(float f) {
    unsigned u = __builtin_bit_cast(unsigned, f);
    return (unsigned short)((u + 0x7FFFu + ((u >> 16) & 1u)) >> 16);
}
__device__ __forceinline__ float bf2f(unsigned short h) {
    return __builtin_bit_cast(float, (unsigned)h << 16);
}

// ---------------- fused prep: BN fold + weight transpose/convert + cnt zero ----
__global__ __launch_bounds__(256) void k_prep(const float* __restrict__ gamma,
                                              const float* __restrict__ beta,
                                              const float* __restrict__ mean,
                                              const float* __restrict__ var,
                                              float* __restrict__ bnscale,
                                              float* __restrict__ bnbias,
                                              const float* __restrict__ W1,
                                              const float* __restrict__ W2,
                                              unsigned short* __restrict__ Wt1,
                                              unsigned short* __restrict__ Wt2,
                                              int* __restrict__ cnt, int n) {
    int i = blockIdx.x * 256 + threadIdx.x;
    if (i < DF * DF) {
        int nn = i / DF, k = i - nn * DF;
        Wt1[i] = f2bf(W1[k * DF + nn]);
        Wt2[i] = f2bf(W2[k * DF + nn]);
    }
    if (i < DF) {
        float s = gamma[i] * rsqrtf(var[i] + BN_EPS);
        bnscale[i] = s;
        bnbias[i]  = beta[i] - mean[i] * s;
    }
    if (i < n) cnt[i] = 0;
}

// count in-degree AND record each edge's rank within its dst bucket
__global__ __launch_bounds__(256) void k_countrank(const int* __restrict__ ei,
                                                   int* __restrict__ cnt,
                                                   int* __restrict__ rank, int E) {
    int e = blockIdx.x * 256 + threadIdx.x;
    if (e < E) rank[e] = atomicAdd(&cnt[ei[E + e]], 1);
}

// per-256-chunk exclusive scan of cnt -> rowptr (pre-offset), chunk totals -> bsum
__global__ __launch_bounds__(256) void k_scan1(const int* __restrict__ cnt,
                                               int* __restrict__ rowptr,
                                               int* __restrict__ bsum, int n) {
    __shared__ int sh[256];
    int t = threadIdx.x;
    int i = blockIdx.x * 256 + t;
    int x = (i < n) ? cnt[i] : 0;
    sh[t] = x;
    __syncthreads();
#pragma unroll
    for (int off = 1; off < 256; off <<= 1) {
        int v = (t >= off) ? sh[t - off] : 0;
        __syncthreads();
        sh[t] += v;
        __syncthreads();
    }
    if (i < n) rowptr[i] = sh[t] - x;
    if (t == 255) bsum[blockIdx.x] = sh[255];
}

// every block redundantly scans bsum in LDS, then finalizes rowptr + dinv
__global__ __launch_bounds__(512) void k_scan23(int* __restrict__ rowptr,
                                                const int* __restrict__ bsum,
                                                const int* __restrict__ cnt,
                                                float* __restrict__ dinv,
                                                int n, int E, int nb) {
    __shared__ int sh[512];
    __shared__ int sbex[512];
    const int t = threadIdx.x;
    int x = (t < nb) ? bsum[t] : 0;
    sh[t] = x;
    __syncthreads();
#pragma unroll
    for (int off = 1; off < 512; off <<= 1) {
        int v = (t >= off) ? sh[t - off] : 0;
        __syncthreads();
        sh[t] += v;
        __syncthreads();
    }
    sbex[t] = sh[t] - x;   // exclusive chunk offsets
    __syncthreads();

    const int i = blockIdx.x * 512 + t;
    if (i < n) {
        rowptr[i] = rowptr[i] + sbex[i >> 8];
        dinv[i]   = rsqrtf((float)cnt[i] + 1.0f);
    }
    if (i == 0) rowptr[n] = E;
}

// atomic-free CSR fill: position = rowptr[dst] + rank[e]
__global__ __launch_bounds__(256) void k_fill(const int* __restrict__ ei,
                                              const int* __restrict__ rowptr,
                                              const int* __restrict__ rank,
                                              int* __restrict__ csr, int E) {
    int e = blockIdx.x * 256 + threadIdx.x;
    if (e < E) {
        int src = ei[e];
        int dst = ei[E + e];
        csr[rowptr[dst] + rank[e]] = src;
    }
}

// ---------------- MFMA GEMM: hs(bf16) = in @ W * dinv[row] ----------------
// LAYER 0: in = fp32 node_feat.  LAYER 1: in = bf16 pre-transformed x2.
// No LDS, no barriers. 4 waves/block, 16 rows/wave, N=96 (6 tiles), K=96 (3 steps).
template <int LAYER>
__global__ __launch_bounds__(256) void k_gemm(const void* __restrict__ in_,
                                              const unsigned short* __restrict__ Wt,
                                              const float* __restrict__ dinv,
                                              unsigned short* __restrict__ outb, int n) {
    const int tid  = threadIdx.x;
    const int wave = tid >> 6;
    const int lane = tid & 63;
    const int l16  = lane & 15;
    const int quad = lane >> 4;
    const int rowbase = blockIdx.x * 64 + wave * 16;
    const int m = rowbase + l16;
    const bool valid = (m < n);

    // B fragments: lane holds B[k=quad*8+j][n=nt*16+l16] = Wt[col][k..k+7]
    bf16x8 bfrag[6][3];
#pragma unroll
    for (int nt = 0; nt < 6; ++nt)
#pragma unroll
        for (int ks = 0; ks < 3; ++ks)
            bfrag[nt][ks] = *(const bf16x8*)&Wt[(nt * 16 + l16) * DF + ks * 32 + quad * 8];

    bf16x8 afrag[3];
    const bf16x8 zf = {};
    if (LAYER == 0) {
        const float* in = (const float*)in_;
        const float* rowp = in + (size_t)m * DF;
        float4 ra[3][2];
#pragma unroll
        for (int ks = 0; ks < 3; ++ks) {
            if (valid) {
                ra[ks][0] = *(const float4*)&rowp[ks * 32 + quad * 8];
                ra[ks][1] = *(const float4*)&rowp[ks * 32 + quad * 8 + 4];
            } else {
                ra[ks][0] = make_float4(0.f, 0.f, 0.f, 0.f);
                ra[ks][1] = make_float4(0.f, 0.f, 0.f, 0.f);
            }
        }
#pragma unroll
        for (int ks = 0; ks < 3; ++ks) {
            const float* a0 = (const float*)&ra[ks][0];
            const float* a1 = (const float*)&ra[ks][1];
            bf16x8 f;
#pragma unroll
            for (int j = 0; j < 4; ++j) {
                f[j]     = (short)f2bf(a0[j]);
                f[j + 4] = (short)f2bf(a1[j]);
            }
            afrag[ks] = f;
        }
    } else {
        const unsigned short* in = (const unsigned short*)in_;
#pragma unroll
        for (int ks = 0; ks < 3; ++ks)
            afrag[ks] = valid ? *(const bf16x8*)&in[(size_t)m * DF + ks * 32 + quad * 8] : zf;
    }

    f32x4 acc[6] = {};
#pragma unroll
    for (int ks = 0; ks < 3; ++ks)
#pragma unroll
        for (int nt = 0; nt < 6; ++nt)
            acc[nt] = __builtin_amdgcn_mfma_f32_16x16x32_bf16(afrag[ks], bfrag[nt][ks],
                                                              acc[nt], 0, 0, 0);

    // D layout: col = l16, row = quad*4 + reg.  Store bf16 with dinv row-scale.
#pragma unroll
    for (int reg = 0; reg < 4; ++reg) {
        const int r = rowbase + quad * 4 + reg;
        if (r < n) {
            const float dv = dinv[r];
#pragma unroll
            for (int nt = 0; nt < 6; ++nt)
                outb[(size_t)r * DF + nt * 16 + l16] = f2bf(acc[nt][reg] * dv);
        }
    }
}

// ---------------- CSR gather over bf16 rows, 12 lanes/node, 16-B loads --------
// LAYER 0: out(bf16) = BN(LeakyReLU(dinv[v]*(self+sum) + b1))   (feeds GEMM2)
// LAYER 1: out(fp32) = dinv[v]*(self+sum) + b2                  (final output)
template <int LAYER>
__global__ __launch_bounds__(GBLK) void k_gather(const int* __restrict__ rowptr,
                                                 const int* __restrict__ csr,
                                                 const unsigned short* __restrict__ hs,
                                                 const float* __restrict__ dinv,
                                                 const float* __restrict__ b1,
                                                 const float* __restrict__ bnscale,
                                                 const float* __restrict__ bnbias,
                                                 const float* __restrict__ b2,
                                                 void* __restrict__ outp, int n) {
    const int t = threadIdx.x;
    const int v = blockIdx.x * NPBG + t / LPN;
    const int q = t % LPN;           // owns bf16 cols [8q, 8q+8)
    if (v >= n) return;

    float acc[8];
    {
        const u16x8 h0 = *(const u16x8*)&hs[(size_t)v * DF + q * 8];  // self-loop
#pragma unroll
        for (int i = 0; i < 8; ++i) acc[i] = bf2f(h0[i]);
    }

    const int e0 = rowptr[v];
    const int e1 = rowptr[v + 1];
    int e = e0;
    // 8-deep unroll: 8 independent 16-B row loads in flight per lane
    for (; e + 8 <= e1; e += 8) {
        int s[8];
#pragma unroll
        for (int u = 0; u < 8; ++u) s[u] = csr[e + u];
        u16x8 m[8];
#pragma unroll
        for (int u = 0; u < 8; ++u) m[u] = *(const u16x8*)&hs[(size_t)s[u] * DF + q * 8];
#pragma unroll
        for (int u = 0; u < 8; ++u)
#pragma unroll
            for (int i = 0; i < 8; ++i) acc[i] += bf2f(m[u][i]);
    }
    for (; e + 4 <= e1; e += 4) {
        int s[4];
#pragma unroll
        for (int u = 0; u < 4; ++u) s[u] = csr[e + u];
        u16x8 m[4];
#pragma unroll
        for (int u = 0; u < 4; ++u) m[u] = *(const u16x8*)&hs[(size_t)s[u] * DF + q * 8];
#pragma unroll
        for (int u = 0; u < 4; ++u)
#pragma unroll
            for (int i = 0; i < 8; ++i) acc[i] += bf2f(m[u][i]);
    }
    for (; e < e1; ++e) {
        const int s = csr[e];
        const u16x8 m = *(const u16x8*)&hs[(size_t)s * DF + q * 8];
#pragma unroll
        for (int i = 0; i < 8; ++i) acc[i] += bf2f(m[i]);
    }

    const float dv = dinv[v];
    if (LAYER == 0) {
        u16x8 o;
#pragma unroll
        for (int i = 0; i < 8; ++i) {
            const int c = q * 8 + i;
            float x = __builtin_fmaf(dv, acc[i], b1[c]);
            x = (x >= 0.f) ? x : SLOPE * x;
            o[i] = f2bf(__builtin_fmaf(x, bnscale[c], bnbias[c]));
        }
        *(u16x8*)((unsigned short*)outp + (size_t)v * DF + q * 8) = o;
    } else {
        float* op = (float*)outp + (size_t)v * DF + q * 8;
        float4 o0, o1;
        o0.x = __builtin_fmaf(acc[0], dv, b2[q * 8 + 0]);
        o0.y = __builtin_fmaf(acc[1], dv, b2[q * 8 + 1]);
        o0.z = __builtin_fmaf(acc[2], dv, b2[q * 8 + 2]);
        o0.w = __builtin_fmaf(acc[3], dv, b2[q * 8 + 3]);
        o1.x = __builtin_fmaf(acc[4], dv, b2[q * 8 + 4]);
        o1.y = __builtin_fmaf(acc[5], dv, b2[q * 8 + 5]);
        o1.z = __builtin_fmaf(acc[6], dv, b2[q * 8 + 6]);
        o1.w = __builtin_fmaf(acc[7], dv, b2[q * 8 + 7]);
        *(float4*)op       = o0;
        *(float4*)(op + 4) = o1;
    }
}

extern "C" void kernel_launch(void* const* d_in, const int* in_sizes, int n_in,
                              void* d_out, int out_size, void* d_ws, size_t ws_size,
                              hipStream_t stream) {
    const float* node_feat = (const float*)d_in[0];
    const int*   ei        = (const int*)d_in[1];
    const float* W1        = (const float*)d_in[2];
    const float* b1        = (const float*)d_in[3];
    const float* W2        = (const float*)d_in[4];
    const float* b2        = (const float*)d_in[5];
    const float* gamma     = (const float*)d_in[6];
    const float* beta      = (const float*)d_in[7];
    const float* mean      = (const float*)d_in[8];
    const float* var       = (const float*)d_in[9];

    const int n  = in_sizes[0] / DF;  // 100000
    const int E  = in_sizes[1] / 2;   // 800000
    const int nb = (n + 255) / 256;   // 391

    char* base = (char*)d_ws;
    size_t off = 0;
    auto alloc = [&](size_t bytes) { void* p = base + off; off = (off + bytes + 15) & ~(size_t)15; return p; };
    int*   cnt     = (int*)alloc(sizeof(int) * n);
    int*   rowptr  = (int*)alloc(sizeof(int) * (n + 1));
    int*   bsum    = (int*)alloc(sizeof(int) * 512);
    float* dinv    = (float*)alloc(sizeof(float) * n);
    float* bnscale = (float*)alloc(sizeof(float) * DF);
    float* bnbias  = (float*)alloc(sizeof(float) * DF);
    unsigned short* Wt1 = (unsigned short*)alloc(sizeof(short) * DF * DF);
    unsigned short* Wt2 = (unsigned short*)alloc(sizeof(short) * DF * DF);
    int*   rank    = (int*)alloc(sizeof(int) * E);
    int*   csr     = (int*)alloc(sizeof(int) * E);
    unsigned short* bufA = (unsigned short*)alloc(sizeof(short) * (size_t)n * DF); // hs1, hs2
    unsigned short* bufB = (unsigned short*)alloc(sizeof(short) * (size_t)n * DF); // x2
    float* out     = (float*)d_out;

    // prep + CSR build
    k_prep<<<nb, 256, 0, stream>>>(gamma, beta, mean, var, bnscale, bnbias,
                                   W1, W2, Wt1, Wt2, cnt, n);
    k_countrank<<<(E + 255) / 256, 256, 0, stream>>>(ei, cnt, rank, E);
    k_scan1<<<nb, 256, 0, stream>>>(cnt, rowptr, bsum, n);
    k_scan23<<<(n + 511) / 512, 512, 0, stream>>>(rowptr, bsum, cnt, dinv, n, E, nb);
    k_fill<<<(E + 255) / 256, 256, 0, stream>>>(ei, rowptr, rank, csr, E);

    const int gblocks  = (n + 63) / 64;
    const int gagather = (n + NPBG - 1) / NPBG;

    // layer 1
    k_gemm<0><<<gblocks, 256, 0, stream>>>(node_feat, Wt1, dinv, bufA, n);
    k_gather<0><<<gagather, GBLK, 0, stream>>>(rowptr, csr, bufA, dinv, b1, bnscale,
                                               bnbias, b2, bufB, n);
    // layer 2
    k_gemm<1><<<gblocks, 256, 0, stream>>>(bufB, Wt2, dinv, bufA, n);
    k_gather<1><<<gagather, GBLK, 0, stream>>>(rowptr, csr, bufA, dinv, b1, bnscale,
                                               bnbias, b2, out, n);
}

// Round 7
// 261.691 us; speedup vs baseline: 8.8178x; 1.0146x over previous
//
#include <hip/hip_runtime.h>

#define DF 96
#define BN_EPS 1e-5f
#define SLOPE 0.05f
#define LPN 12            // lanes per node in gather
#define GBLK 192          // gather block threads
#define NPBG (GBLK / LPN) // 16 nodes per gather block

typedef __attribute__((ext_vector_type(8))) short bf16x8;
typedef __attribute__((ext_vector_type(4))) float f32x4;
typedef __attribute__((ext_vector_type(8))) unsigned short u16x8;

__device__ __forceinline__ unsigned short f2bf(float f) {
    unsigned u = __builtin_bit_cast(unsigned, f);
    return (unsigned short)((u + 0x7FFFu + ((u >> 16) & 1u)) >> 16);
}
__device__ __forceinline__ float bf2f(unsigned short h) {
    return __builtin_bit_cast(float, (unsigned)h << 16);
}

// ---------------- fused prep: BN fold + weight transpose/convert + cnt zero ----
__global__ __launch_bounds__(256) void k_prep(const float* __restrict__ gamma,
                                              const float* __restrict__ beta,
                                              const float* __restrict__ mean,
                                              const float* __restrict__ var,
                                              float* __restrict__ bnscale,
                                              float* __restrict__ bnbias,
                                              const float* __restrict__ W1,
                                              const float* __restrict__ W2,
                                              unsigned short* __restrict__ Wt1,
                                              unsigned short* __restrict__ Wt2,
                                              int* __restrict__ cnt, int n) {
    int i = blockIdx.x * 256 + threadIdx.x;
    if (i < DF * DF) {
        int nn = i / DF, k = i - nn * DF;
        Wt1[i] = f2bf(W1[k * DF + nn]);
        Wt2[i] = f2bf(W2[k * DF + nn]);
    }
    if (i < DF) {
        float s = gamma[i] * rsqrtf(var[i] + BN_EPS);
        bnscale[i] = s;
        bnbias[i]  = beta[i] - mean[i] * s;
    }
    if (i < n) cnt[i] = 0;
}

// count in-degree AND record each edge's rank within its dst bucket (2 edges/thread)
__global__ __launch_bounds__(256) void k_countrank(const int* __restrict__ ei,
                                                   int* __restrict__ cnt,
                                                   int* __restrict__ rank, int E) {
    int i = blockIdx.x * 256 + threadIdx.x;
    int e = i * 2;
    if (e + 1 < E) {
        int2 d = *(const int2*)&ei[E + e];
        int r0 = atomicAdd(&cnt[d.x], 1);
        int r1 = atomicAdd(&cnt[d.y], 1);
        *(int2*)&rank[e] = make_int2(r0, r1);
    } else if (e < E) {
        rank[e] = atomicAdd(&cnt[ei[E + e]], 1);
    }
}

// per-256-chunk exclusive scan of cnt -> rowptr (pre-offset), chunk totals -> bsum
__global__ __launch_bounds__(256) void k_scan1(const int* __restrict__ cnt,
                                               int* __restrict__ rowptr,
                                               int* __restrict__ bsum, int n) {
    __shared__ int sh[256];
    int t = threadIdx.x;
    int i = blockIdx.x * 256 + t;
    int x = (i < n) ? cnt[i] : 0;
    sh[t] = x;
    __syncthreads();
#pragma unroll
    for (int off = 1; off < 256; off <<= 1) {
        int v = (t >= off) ? sh[t - off] : 0;
        __syncthreads();
        sh[t] += v;
        __syncthreads();
    }
    if (i < n) rowptr[i] = sh[t] - x;
    if (t == 255) bsum[blockIdx.x] = sh[255];
}

// every block redundantly scans bsum in LDS, then finalizes rowptr + dinv
__global__ __launch_bounds__(512) void k_scan23(int* __restrict__ rowptr,
                                                const int* __restrict__ bsum,
                                                const int* __restrict__ cnt,
                                                float* __restrict__ dinv,
                                                int n, int E, int nb) {
    __shared__ int sh[512];
    __shared__ int sbex[512];
    const int t = threadIdx.x;
    int x = (t < nb) ? bsum[t] : 0;
    sh[t] = x;
    __syncthreads();
#pragma unroll
    for (int off = 1; off < 512; off <<= 1) {
        int v = (t >= off) ? sh[t - off] : 0;
        __syncthreads();
        sh[t] += v;
        __syncthreads();
    }
    sbex[t] = sh[t] - x;   // exclusive chunk offsets
    __syncthreads();

    const int i = blockIdx.x * 512 + t;
    if (i < n) {
        rowptr[i] = rowptr[i] + sbex[i >> 8];
        dinv[i]   = rsqrtf((float)cnt[i] + 1.0f);
    }
    if (i == 0) rowptr[n] = E;
}

// ---------------- GEMM body: hs(bf16) = in @ W * dinv[row] ----------------
// LAYER 0: in = fp32 node_feat.  LAYER 1: in = bf16 pre-transformed x2.
// No LDS, no barriers. 4 waves/block, 16 rows/wave, N=96 (6 tiles), K=96 (3 steps).
template <int LAYER>
__device__ __forceinline__ void gemm_body(int bid, int tid, const void* __restrict__ in_,
                                          const unsigned short* __restrict__ Wt,
                                          const float* __restrict__ dinv,
                                          unsigned short* __restrict__ outb, int n) {
    const int wave = tid >> 6;
    const int lane = tid & 63;
    const int l16  = lane & 15;
    const int quad = lane >> 4;
    const int rowbase = bid * 64 + wave * 16;
    const int m = rowbase + l16;
    const bool valid = (m < n);

    // B fragments: lane holds B[k=quad*8+j][n=nt*16+l16] = Wt[col][k..k+7]
    bf16x8 bfrag[6][3];
#pragma unroll
    for (int nt = 0; nt < 6; ++nt)
#pragma unroll
        for (int ks = 0; ks < 3; ++ks)
            bfrag[nt][ks] = *(const bf16x8*)&Wt[(nt * 16 + l16) * DF + ks * 32 + quad * 8];

    bf16x8 afrag[3];
    const bf16x8 zf = {};
    if (LAYER == 0) {
        const float* in = (const float*)in_;
        const float* rowp = in + (size_t)m * DF;
        float4 ra[3][2];
#pragma unroll
        for (int ks = 0; ks < 3; ++ks) {
            if (valid) {
                ra[ks][0] = *(const float4*)&rowp[ks * 32 + quad * 8];
                ra[ks][1] = *(const float4*)&rowp[ks * 32 + quad * 8 + 4];
            } else {
                ra[ks][0] = make_float4(0.f, 0.f, 0.f, 0.f);
                ra[ks][1] = make_float4(0.f, 0.f, 0.f, 0.f);
            }
        }
#pragma unroll
        for (int ks = 0; ks < 3; ++ks) {
            const float* a0 = (const float*)&ra[ks][0];
            const float* a1 = (const float*)&ra[ks][1];
            bf16x8 f;
#pragma unroll
            for (int j = 0; j < 4; ++j) {
                f[j]     = (short)f2bf(a0[j]);
                f[j + 4] = (short)f2bf(a1[j]);
            }
            afrag[ks] = f;
        }
    } else {
        const unsigned short* in = (const unsigned short*)in_;
#pragma unroll
        for (int ks = 0; ks < 3; ++ks)
            afrag[ks] = valid ? *(const bf16x8*)&in[(size_t)m * DF + ks * 32 + quad * 8] : zf;
    }

    f32x4 acc[6] = {};
#pragma unroll
    for (int ks = 0; ks < 3; ++ks)
#pragma unroll
        for (int nt = 0; nt < 6; ++nt)
            acc[nt] = __builtin_amdgcn_mfma_f32_16x16x32_bf16(afrag[ks], bfrag[nt][ks],
                                                              acc[nt], 0, 0, 0);

    // D layout: col = l16, row = quad*4 + reg.  Store bf16 with dinv row-scale.
#pragma unroll
    for (int reg = 0; reg < 4; ++reg) {
        const int r = rowbase + quad * 4 + reg;
        if (r < n) {
            const float dv = dinv[r];
#pragma unroll
            for (int nt = 0; nt < 6; ++nt)
                outb[(size_t)r * DF + nt * 16 + l16] = f2bf(acc[nt][reg] * dv);
        }
    }
}

// atomic-free CSR fill body: position = rowptr[dst] + rank[e]
__device__ __forceinline__ void fill_body(int bid, int tid, const int* __restrict__ ei,
                                          const int* __restrict__ rowptr,
                                          const int* __restrict__ rank,
                                          int* __restrict__ csr, int E) {
    int e = bid * 256 + tid;
    if (e < E) {
        int src = ei[e];
        int dst = ei[E + e];
        csr[rowptr[dst] + rank[e]] = src;
    }
}

// fused: blocks [0, gb) run GEMM layer-1, blocks [gb, ...) run CSR fill.
// Independent work, different pipes (MFMA+stream vs random scatter) -> overlap.
__global__ __launch_bounds__(256) void k_gemm1_fill(const float* __restrict__ in,
                                                    const unsigned short* __restrict__ Wt1,
                                                    const float* __restrict__ dinv,
                                                    unsigned short* __restrict__ bufA,
                                                    int n, int gb,
                                                    const int* __restrict__ ei,
                                                    const int* __restrict__ rowptr,
                                                    const int* __restrict__ rank,
                                                    int* __restrict__ csr, int E) {
    const int b = blockIdx.x;
    if (b < gb) gemm_body<0>(b, threadIdx.x, in, Wt1, dinv, bufA, n);
    else        fill_body(b - gb, threadIdx.x, ei, rowptr, rank, csr, E);
}

__global__ __launch_bounds__(256) void k_gemm2(const unsigned short* __restrict__ in,
                                               const unsigned short* __restrict__ Wt2,
                                               const float* __restrict__ dinv,
                                               unsigned short* __restrict__ outb, int n) {
    gemm_body<1>(blockIdx.x, threadIdx.x, in, Wt2, dinv, outb, n);
}

// ---------------- CSR gather over bf16 rows, 12 lanes/node, 16-B loads --------
// LAYER 0: out(bf16) = BN(LeakyReLU(dinv[v]*(self+sum) + b1))   (feeds GEMM2)
// LAYER 1: out(fp32) = dinv[v]*(self+sum) + b2                  (final output)
template <int LAYER>
__global__ __launch_bounds__(GBLK) void k_gather(const int* __restrict__ rowptr,
                                                 const int* __restrict__ csr,
                                                 const unsigned short* __restrict__ hs,
                                                 const float* __restrict__ dinv,
                                                 const float* __restrict__ b1,
                                                 const float* __restrict__ bnscale,
                                                 const float* __restrict__ bnbias,
                                                 const float* __restrict__ b2,
                                                 void* __restrict__ outp, int n) {
    const int t = threadIdx.x;
    const int v = blockIdx.x * NPBG + t / LPN;
    const int q = t % LPN;           // owns bf16 cols [8q, 8q+8)
    if (v >= n) return;

    float acc[8];
    {
        const u16x8 h0 = *(const u16x8*)&hs[(size_t)v * DF + q * 8];  // self-loop
#pragma unroll
        for (int i = 0; i < 8; ++i) acc[i] = bf2f(h0[i]);
    }

    const int e0 = rowptr[v];
    const int e1 = rowptr[v + 1];
    int e = e0;
    for (; e + 8 <= e1; e += 8) {
        int s[8];
#pragma unroll
        for (int u = 0; u < 8; ++u) s[u] = csr[e + u];
        u16x8 m[8];
#pragma unroll
        for (int u = 0; u < 8; ++u) m[u] = *(const u16x8*)&hs[(size_t)s[u] * DF + q * 8];
#pragma unroll
        for (int u = 0; u < 8; ++u)
#pragma unroll
            for (int i = 0; i < 8; ++i) acc[i] += bf2f(m[u][i]);
    }
    for (; e + 4 <= e1; e += 4) {
        int s[4];
#pragma unroll
        for (int u = 0; u < 4; ++u) s[u] = csr[e + u];
        u16x8 m[4];
#pragma unroll
        for (int u = 0; u < 4; ++u) m[u] = *(const u16x8*)&hs[(size_t)s[u] * DF + q * 8];
#pragma unroll
        for (int u = 0; u < 4; ++u)
#pragma unroll
            for (int i = 0; i < 8; ++i) acc[i] += bf2f(m[u][i]);
    }
    for (; e < e1; ++e) {
        const int s = csr[e];
        const u16x8 m = *(const u16x8*)&hs[(size_t)s * DF + q * 8];
#pragma unroll
        for (int i = 0; i < 8; ++i) acc[i] += bf2f(m[i]);
    }

    const float dv = dinv[v];
    if (LAYER == 0) {
        u16x8 o;
#pragma unroll
        for (int i = 0; i < 8; ++i) {
            const int c = q * 8 + i;
            float x = __builtin_fmaf(dv, acc[i], b1[c]);
            x = (x >= 0.f) ? x : SLOPE * x;
            o[i] = f2bf(__builtin_fmaf(x, bnscale[c], bnbias[c]));
        }
        *(u16x8*)((unsigned short*)outp + (size_t)v * DF + q * 8) = o;
    } else {
        float* op = (float*)outp + (size_t)v * DF + q * 8;
        float4 o0, o1;
        o0.x = __builtin_fmaf(acc[0], dv, b2[q * 8 + 0]);
        o0.y = __builtin_fmaf(acc[1], dv, b2[q * 8 + 1]);
        o0.z = __builtin_fmaf(acc[2], dv, b2[q * 8 + 2]);
        o0.w = __builtin_fmaf(acc[3], dv, b2[q * 8 + 3]);
        o1.x = __builtin_fmaf(acc[4], dv, b2[q * 8 + 4]);
        o1.y = __builtin_fmaf(acc[5], dv, b2[q * 8 + 5]);
        o1.z = __builtin_fmaf(acc[6], dv, b2[q * 8 + 6]);
        o1.w = __builtin_fmaf(acc[7], dv, b2[q * 8 + 7]);
        *(float4*)op       = o0;
        *(float4*)(op + 4) = o1;
    }
}

extern "C" void kernel_launch(void* const* d_in, const int* in_sizes, int n_in,
                              void* d_out, int out_size, void* d_ws, size_t ws_size,
                              hipStream_t stream) {
    const float* node_feat = (const float*)d_in[0];
    const int*   ei        = (const int*)d_in[1];
    const float* W1        = (const float*)d_in[2];
    const float* b1        = (const float*)d_in[3];
    const float* W2        = (const float*)d_in[4];
    const float* b2        = (const float*)d_in[5];
    const float* gamma     = (const float*)d_in[6];
    const float* beta      = (const float*)d_in[7];
    const float* mean      = (const float*)d_in[8];
    const float* var       = (const float*)d_in[9];

    const int n  = in_sizes[0] / DF;  // 100000
    const int E  = in_sizes[1] / 2;   // 800000
    const int nb = (n + 255) / 256;   // 391

    char* base = (char*)d_ws;
    size_t off = 0;
    auto alloc = [&](size_t bytes) { void* p = base + off; off = (off + bytes + 15) & ~(size_t)15; return p; };
    int*   cnt     = (int*)alloc(sizeof(int) * n);
    int*   rowptr  = (int*)alloc(sizeof(int) * (n + 1));
    int*   bsum    = (int*)alloc(sizeof(int) * 512);
    float* dinv    = (float*)alloc(sizeof(float) * n);
    float* bnscale = (float*)alloc(sizeof(float) * DF);
    float* bnbias  = (float*)alloc(sizeof(float) * DF);
    unsigned short* Wt1 = (unsigned short*)alloc(sizeof(short) * DF * DF);
    unsigned short* Wt2 = (unsigned short*)alloc(sizeof(short) * DF * DF);
    int*   rank    = (int*)alloc(sizeof(int) * E);
    int*   csr     = (int*)alloc(sizeof(int) * E);
    unsigned short* bufA = (unsigned short*)alloc(sizeof(short) * (size_t)n * DF); // hs1, hs2
    unsigned short* bufB = (unsigned short*)alloc(sizeof(short) * (size_t)n * DF); // x2
    float* out     = (float*)d_out;

    // prep + CSR build
    k_prep<<<nb, 256, 0, stream>>>(gamma, beta, mean, var, bnscale, bnbias,
                                   W1, W2, Wt1, Wt2, cnt, n);
    k_countrank<<<(E / 2 + 255) / 256, 256, 0, stream>>>(ei, cnt, rank, E);
    k_scan1<<<nb, 256, 0, stream>>>(cnt, rowptr, bsum, n);
    k_scan23<<<(n + 511) / 512, 512, 0, stream>>>(rowptr, bsum, cnt, dinv, n, E, nb);

    const int gb = (n + 63) / 64;            // gemm blocks
    const int fb = (E + 255) / 256;          // fill blocks
    const int gagather = (n + NPBG - 1) / NPBG;

    // layer 1 GEMM overlapped with CSR fill (independent after scan23)
    k_gemm1_fill<<<gb + fb, 256, 0, stream>>>(node_feat, Wt1, dinv, bufA, n, gb,
                                              ei, rowptr, rank, csr, E);
    k_gather<0><<<gagather, GBLK, 0, stream>>>(rowptr, csr, bufA, dinv, b1, bnscale,
                                               bnbias, b2, bufB, n);
    // layer 2
    k_gemm2<<<gb, 256, 0, stream>>>(bufB, Wt2, dinv, bufA, n);
    k_gather<1><<<gagather, GBLK, 0, stream>>>(rowptr, csr, bufA, dinv, b1, bnscale,
                                               bnbias, b2, out, n);
}